// Round 10
// baseline (1590.227 us; speedup 1.0000x reference)
//
#include <hip/hip_runtime.h>
#include <hip/hip_fp16.h>

#define NN 100000
#define NE 1600000
#define CHUNK 1024
#define NCHUNK ((NN + CHUNK - 1) / CHUNK)
#define NBUCK 196            // dst >> 9  (512 nodes per bucket)
#define BCAP 9216            // mean 8192, sigma ~90 -> +11 sigma
#define PA_EDGES 4096

union H2x4 { uint4 u; __half2 h[4]; };

// ---------------- CSR build: two-pass LDS radix binning ----------------

__global__ __launch_bounds__(256) void binA_kernel(const int* __restrict__ src,
                                                   const int* __restrict__ dst,
                                                   int* __restrict__ gcnt,
                                                   unsigned* __restrict__ bins) {
    __shared__ int lcnt[256], lofs[256], lfil[256], gbase[256];
    __shared__ unsigned stage[PA_EDGES];
    const int tid = threadIdx.x;
    const int e0 = blockIdx.x * PA_EDGES;
    lcnt[tid] = 0; lfil[tid] = 0;
    __syncthreads();
    for (int k = 0; k < PA_EDGES / 256; ++k) {
        const int e = e0 + k * 256 + tid;
        if (e < NE) atomicAdd(&lcnt[dst[e] >> 9], 1);
    }
    __syncthreads();
    const int v = lcnt[tid];
    lofs[tid] = v;
    __syncthreads();
    for (int off = 1; off < 256; off <<= 1) {
        int xv = (tid >= off) ? lofs[tid - off] : 0;
        __syncthreads();
        lofs[tid] += xv;
        __syncthreads();
    }
    const int excl = lofs[tid] - v;
    __syncthreads();
    lofs[tid] = excl;
    if (tid < NBUCK && v > 0) gbase[tid] = atomicAdd(&gcnt[tid], v);
    else gbase[tid] = 0;
    __syncthreads();
    for (int k = 0; k < PA_EDGES / 256; ++k) {
        const int e = e0 + k * 256 + tid;
        if (e < NE) {
            const int d = dst[e];
            const int b = d >> 9;
            const int p = atomicAdd(&lfil[b], 1);
            stage[lofs[b] + p] = ((unsigned)src[e] << 9) | (unsigned)(d & 511);
        }
    }
    __syncthreads();
    const int wave = tid >> 6, lane = tid & 63;
    for (int b = wave; b < NBUCK; b += 4) {
        const int n = lcnt[b];
        const int base = gbase[b];
        const int off = lofs[b];
        for (int k = lane; k < n; k += 64) {
            const int gpos = base + k;
            if (gpos < BCAP) bins[(size_t)b * BCAP + gpos] = stage[off + k];
        }
    }
}

__global__ __launch_bounds__(256) void binB1_kernel(const unsigned* __restrict__ bins,
                                                    const int* __restrict__ gcnt,
                                                    int* __restrict__ cnt) {
    __shared__ int c512[512];
    const int b = blockIdx.x, tid = threadIdx.x;
    c512[tid] = 0; c512[256 + tid] = 0;
    __syncthreads();
    const int n = min(gcnt[b], BCAP);
    for (int k = tid; k < n; k += 256)
        atomicAdd(&c512[bins[(size_t)b * BCAP + k] & 511], 1);
    __syncthreads();
    const int i0 = b * 512 + tid;
    const int i1 = i0 + 256;
    if (i0 < NN) cnt[i0] = c512[tid];
    if (i1 < NN) cnt[i1] = c512[256 + tid];
}

__global__ __launch_bounds__(256) void binB2_kernel(const unsigned* __restrict__ bins,
                                                    const int* __restrict__ gcnt,
                                                    const int* __restrict__ rptr,
                                                    int* __restrict__ col) {
    __shared__ int fil512[512];
    __shared__ int rp_l[512];
    const int b = blockIdx.x, tid = threadIdx.x;
    fil512[tid] = 0; fil512[256 + tid] = 0;
    const int i0 = b * 512 + tid;
    const int i1 = i0 + 256;
    rp_l[tid]       = (i0 < NN) ? rptr[i0] : 0;
    rp_l[256 + tid] = (i1 < NN) ? rptr[i1] : 0;
    __syncthreads();
    const int n = min(gcnt[b], BCAP);
    for (int k = tid; k < n; k += 256) {
        const unsigned w = bins[(size_t)b * BCAP + k];
        const int dl = (int)(w & 511);
        const int s = (int)(w >> 9);
        const int p = atomicAdd(&fil512[dl], 1);
        col[rp_l[dl] + p] = s;
    }
}

// dis[i] = rsqrt(deg_i+1);  xs4 = dis-prescaled x rows, padded to float4
__global__ void dis_xs_kernel(const int* __restrict__ cnt, const float* __restrict__ x,
                              float* __restrict__ dis, float4* __restrict__ xs4) {
    int i = blockIdx.x * blockDim.x + threadIdx.x;
    if (i >= NN) return;
    float d = rsqrtf((float)(cnt[i] + 1));
    dis[i] = d;
    xs4[i] = make_float4(d * x[i * 3 + 0], d * x[i * 3 + 1], d * x[i * 3 + 2], 0.f);
}

// hierarchical exclusive scan of (cnt[i]+1)  [self-loop included in CSR]
__global__ __launch_bounds__(256) void scan1_kernel(const int* __restrict__ cnt,
                                                    int* __restrict__ row_ptr,
                                                    int* __restrict__ sums) {
    __shared__ int sdata[256];
    const int b = blockIdx.x, t = threadIdx.x;
    const int base = b * CHUNK + t * 4;
    int v0 = (base + 0 < NN) ? cnt[base + 0] + 1 : 0;
    int v1 = (base + 1 < NN) ? cnt[base + 1] + 1 : 0;
    int v2 = (base + 2 < NN) ? cnt[base + 2] + 1 : 0;
    int v3 = (base + 3 < NN) ? cnt[base + 3] + 1 : 0;
    const int s = v0 + v1 + v2 + v3;
    sdata[t] = s;
    __syncthreads();
    for (int off = 1; off < 256; off <<= 1) {
        int xv = (t >= off) ? sdata[t - off] : 0;
        __syncthreads();
        sdata[t] += xv;
        __syncthreads();
    }
    const int excl = sdata[t] - s;
    if (base + 0 < NN) row_ptr[base + 0] = excl;
    if (base + 1 < NN) row_ptr[base + 1] = excl + v0;
    if (base + 2 < NN) row_ptr[base + 2] = excl + v0 + v1;
    if (base + 3 < NN) row_ptr[base + 3] = excl + v0 + v1 + v2;
    if (t == 255) sums[b] = sdata[255];
}

__global__ __launch_bounds__(128) void scan2_kernel(int* __restrict__ sums,
                                                    int* __restrict__ row_ptr) {
    __shared__ int sd[128];
    const int t = threadIdx.x;
    const int v = (t < NCHUNK) ? sums[t] : 0;
    sd[t] = v;
    __syncthreads();
    for (int off = 1; off < 128; off <<= 1) {
        int xv = (t >= off) ? sd[t - off] : 0;
        __syncthreads();
        sd[t] += xv;
        __syncthreads();
    }
    if (t < NCHUNK) sums[t] = sd[t] - v;
    if (t == 127) row_ptr[NN] = sd[127];
}

__global__ void scan3_kernel(int* __restrict__ row_ptr, const int* __restrict__ sums) {
    int i = blockIdx.x * blockDim.x + threadIdx.x;
    if (i < NN) row_ptr[i] += sums[i >> 10];
}

__global__ void selffill_kernel(const int* __restrict__ row_ptr, const int* __restrict__ cnt,
                                int* __restrict__ col) {
    int i = blockIdx.x * blockDim.x + threadIdx.x;
    if (i >= NN) return;
    col[row_ptr[i] + cnt[i]] = i;  // self edge last in the row
}

// ax = Ahat @ x = dis_i * sum_j xs[j]   (CSR includes self loop)
__global__ void aggx_kernel(const float4* __restrict__ xs4, const int* __restrict__ row_ptr,
                            const int* __restrict__ col, const float* __restrict__ dis,
                            float* __restrict__ ax) {
    int i = blockIdx.x * blockDim.x + threadIdx.x;
    if (i >= NN) return;
    float a0 = 0.f, a1 = 0.f, a2 = 0.f;
    const int s = row_ptr[i], e = row_ptr[i + 1];
    int p = s;
    for (; p + 2 <= e; p += 2) {
        const float4 v0 = xs4[col[p]];
        const float4 v1 = xs4[col[p + 1]];
        a0 += v0.x + v1.x; a1 += v0.y + v1.y; a2 += v0.z + v1.z;
    }
    if (p < e) {
        const float4 v = xs4[col[p]];
        a0 += v.x; a1 += v.y; a2 += v.z;
    }
    const float d = dis[i];
    ax[i * 3 + 0] = d * a0; ax[i * 3 + 1] = d * a1; ax[i * 3 + 2] = d * a2;
}

// t16 = fp16(dis * relu(ax @ Wp + bp));  xr = ax @ Wr[64:67,:] + br
__global__ void proj_kernel(const float* __restrict__ ax,
                            const float* __restrict__ Wp, const float* __restrict__ bp,
                            const float* __restrict__ Wr, const float* __restrict__ br,
                            const float* __restrict__ dis,
                            __half* __restrict__ t16, float* __restrict__ xr) {
    int g = blockIdx.x * blockDim.x + threadIdx.x;
    if (g >= NN * 64) return;
    int i = g >> 6, c = g & 63;
    float a0 = ax[i * 3 + 0], a1 = ax[i * 3 + 1], a2 = ax[i * 3 + 2];
    float tp = fmaxf(a0 * Wp[c] + a1 * Wp[64 + c] + a2 * Wp[128 + c] + bp[c], 0.f);
    t16[g] = __float2half(tp * dis[i]);
    xr[g] = a0 * Wr[64 * 64 + c] + a1 * Wr[65 * 64 + c] + a2 * Wr[66 * 64 + c] + br[c];
}

// head dense: z1 = bt16 @ Wh1  (rows already dis-prescaled; multiply-first)
__global__ void mmh1_kernel(const __half* __restrict__ bt, const float* __restrict__ Wh1,
                            __half* __restrict__ z1) {
    int g = blockIdx.x * blockDim.x + threadIdx.x;
    if (g >= NN * 32) return;
    const int i = g >> 5, c = g & 31;
    const __half* row = bt + (size_t)i * 64;
    float acc = 0.f;
#pragma unroll
    for (int k4 = 0; k4 < 8; ++k4) {
        H2x4 r;
        r.u = ((const uint4*)row)[k4];
#pragma unroll
        for (int t = 0; t < 4; ++t) {
            const float2 f = __half22float2(r.h[t]);
            acc += f.x * Wh1[(k4 * 8 + 2 * t) * 32 + c];
            acc += f.y * Wh1[(k4 * 8 + 2 * t + 1) * 32 + c];
        }
    }
    z1[g] = __float2half(acc);
}

// head final: out = dis_i * sum_j z3[j] + bh3   (2-wide rows, L2-resident)
__global__ void final2_kernel(const __half* __restrict__ z3, const int* __restrict__ rptr,
                              const int* __restrict__ col, const float* __restrict__ dis,
                              const float* __restrict__ bh3, float* __restrict__ out) {
    int i = blockIdx.x * blockDim.x + threadIdx.x;
    if (i >= NN) return;
    const int s = rptr[i], e = rptr[i + 1];
    float a0 = 0.f, a1 = 0.f;
    int p = s;
    for (; p + 2 <= e; p += 2) {
        const __half2 h0 = ((const __half2*)z3)[col[p]];
        const __half2 h1 = ((const __half2*)z3)[col[p + 1]];
        const float2 f0 = __half22float2(h0);
        const float2 f1 = __half22float2(h1);
        a0 += f0.x + f1.x; a1 += f0.y + f1.y;
    }
    if (p < e) {
        const float2 f = __half22float2(((const __half2*)z3)[col[p]]);
        a0 += f.x; a1 += f.y;
    }
    const float d = dis[i];
    out[2 * i]     = d * a0 + bh3[0];
    out[2 * i + 1] = d * a1 + bh3[1];
}

// ---------------- fused GCN ----------------
// h16 rows fp16, pre-scaled by dis[j]. agg_i = dis_i * sum_{j in row} h16[j].
// Phase 1: two rows jointly, straight-line, named vars only (R7 lesson).
// PRE mode (head layers, multiply-first): phase-1 epilogue applies
// relu(dis*agg + bias)*dis; phase 2 multiplies by NEXT layer's W and writes
// raw fp16 (already prescaled). STD mode: phase 2 = aggT@W + bias [+add][relu].

template <int IN_W, int OUT_W, bool RELU, bool HAS_ADD, bool HAS_BIAS, bool W32, bool W16,
          bool PRE = false>
__global__ __launch_bounds__(256, 4) void gcn_kernel(
    const __half* __restrict__ h16, const float* __restrict__ Wg,
    const float* __restrict__ bias, const float* __restrict__ addsrc,
    const int* __restrict__ row_ptr, const int* __restrict__ colv,
    const float* __restrict__ dis,
    float* __restrict__ out32, __half* __restrict__ out16) {
    constexpr int TILE_R = 64;
    constexpr int QUADS = IN_W / 8;      // lanes per row (16B = 8 halves each)
    constexpr int SLOTS = 64 / QUADS;    // rows gathered per wave instruction
    constexpr int STR = IN_W + 4;
    __shared__ __align__(16) float aggT[TILE_R][STR];
    __shared__ int rp[TILE_R + 1];
    __shared__ float rdis[TILE_R];

    const int tid = threadIdx.x;
    const int tile0 = blockIdx.x * TILE_R;

    if (tid <= TILE_R) rp[tid] = row_ptr[min(tile0 + tid, NN)];
    if (tid < TILE_R) {
        const int i = tile0 + tid;
        rdis[tid] = (i < NN) ? dis[i] : 0.f;
    }
    __syncthreads();

    const int wave = tid >> 6;
    const int lane = tid & 63;
    const int fq = lane & (QUADS - 1);
    const int slot = lane / QUADS;
    const int rbase = wave << 4;
    const size_t fqo = (size_t)(fq << 3);

    float blf[8];
    if constexpr (PRE) {
#pragma unroll
        for (int t = 0; t < 8; ++t) blf[t] = bias[(fq << 3) + t];
    }

    const __half2 ONE2 = __float2half2_rn(1.0f);
    const __half2 ZERO2 = __float2half2_rn(0.0f);

    for (int hr = 0; hr < 8; ++hr) {
        const int rA = rbase + 2 * hr;
        const int rB = rA + 1;
        const int sA = __builtin_amdgcn_readfirstlane(rp[rA]);
        const int eA = __builtin_amdgcn_readfirstlane(rp[rA + 1]);
        const int sB = eA;
        const int eB = __builtin_amdgcn_readfirstlane(rp[rB + 1]);
        const int lastA = eA - 1, lastB = eB - 1;
        const int pA = sA + slot, pB = sB + slot;

        const int jA0 = colv[min(pA, lastA)];
        const int jA1 = colv[min(pA + SLOTS, lastA)];
        const int jA2 = colv[min(pA + 2 * SLOTS, lastA)];
        const int jA3 = colv[min(pA + 3 * SLOTS, lastA)];
        const int jB0 = colv[min(pB, lastB)];
        const int jB1 = colv[min(pB + SLOTS, lastB)];
        const int jB2 = colv[min(pB + 2 * SLOTS, lastB)];
        const int jB3 = colv[min(pB + 3 * SLOTS, lastB)];
        const uint4 gA0 = *(const uint4*)(h16 + (size_t)jA0 * IN_W + fqo);
        const uint4 gA1 = *(const uint4*)(h16 + (size_t)jA1 * IN_W + fqo);
        const uint4 gA2 = *(const uint4*)(h16 + (size_t)jA2 * IN_W + fqo);
        const uint4 gA3 = *(const uint4*)(h16 + (size_t)jA3 * IN_W + fqo);
        const uint4 gB0 = *(const uint4*)(h16 + (size_t)jB0 * IN_W + fqo);
        const uint4 gB1 = *(const uint4*)(h16 + (size_t)jB1 * IN_W + fqo);
        const uint4 gB2 = *(const uint4*)(h16 + (size_t)jB2 * IN_W + fqo);
        const uint4 gB3 = *(const uint4*)(h16 + (size_t)jB3 * IN_W + fqo);

        __half2 aA[4] = {ZERO2, ZERO2, ZERO2, ZERO2};
        __half2 aB[4] = {ZERO2, ZERO2, ZERO2, ZERO2};
        {
            H2x4 hh;
            const __half2 mA0 = (pA < eA) ? ONE2 : ZERO2;
            const __half2 mA1 = (pA + SLOTS < eA) ? ONE2 : ZERO2;
            const __half2 mA2 = (pA + 2 * SLOTS < eA) ? ONE2 : ZERO2;
            const __half2 mA3 = (pA + 3 * SLOTS < eA) ? ONE2 : ZERO2;
            const __half2 mB0 = (pB < eB) ? ONE2 : ZERO2;
            const __half2 mB1 = (pB + SLOTS < eB) ? ONE2 : ZERO2;
            const __half2 mB2 = (pB + 2 * SLOTS < eB) ? ONE2 : ZERO2;
            const __half2 mB3 = (pB + 3 * SLOTS < eB) ? ONE2 : ZERO2;
            hh.u = gA0;
#pragma unroll
            for (int t = 0; t < 4; ++t) aA[t] = __hfma2(hh.h[t], mA0, aA[t]);
            hh.u = gA1;
#pragma unroll
            for (int t = 0; t < 4; ++t) aA[t] = __hfma2(hh.h[t], mA1, aA[t]);
            hh.u = gA2;
#pragma unroll
            for (int t = 0; t < 4; ++t) aA[t] = __hfma2(hh.h[t], mA2, aA[t]);
            hh.u = gA3;
#pragma unroll
            for (int t = 0; t < 4; ++t) aA[t] = __hfma2(hh.h[t], mA3, aA[t]);
            hh.u = gB0;
#pragma unroll
            for (int t = 0; t < 4; ++t) aB[t] = __hfma2(hh.h[t], mB0, aB[t]);
            hh.u = gB1;
#pragma unroll
            for (int t = 0; t < 4; ++t) aB[t] = __hfma2(hh.h[t], mB1, aB[t]);
            hh.u = gB2;
#pragma unroll
            for (int t = 0; t < 4; ++t) aB[t] = __hfma2(hh.h[t], mB2, aB[t]);
            hh.u = gB3;
#pragma unroll
            for (int t = 0; t < 4; ++t) aB[t] = __hfma2(hh.h[t], mB3, aB[t]);
        }
        if (eA - sA > 4 * SLOTS) {
            H2x4 hh;
            for (int p = pA + 4 * SLOTS; p < eA; p += SLOTS) {
                hh.u = *(const uint4*)(h16 + (size_t)colv[p] * IN_W + fqo);
#pragma unroll
                for (int t = 0; t < 4; ++t) aA[t] = __hadd2(aA[t], hh.h[t]);
            }
        }
        if (eB - sB > 4 * SLOTS) {
            H2x4 hh;
            for (int p = pB + 4 * SLOTS; p < eB; p += SLOTS) {
                hh.u = *(const uint4*)(h16 + (size_t)colv[p] * IN_W + fqo);
#pragma unroll
                for (int t = 0; t < 4; ++t) aB[t] = __hadd2(aB[t], hh.h[t]);
            }
        }
#pragma unroll
        for (int t = 0; t < 4; ++t) {
            int vA = __shfl_xor(*reinterpret_cast<const int*>(&aA[t]), QUADS, 64);
            int vB = __shfl_xor(*reinterpret_cast<const int*>(&aB[t]), QUADS, 64);
            aA[t] = __hadd2(aA[t], *reinterpret_cast<const __half2*>(&vA));
            aB[t] = __hadd2(aB[t], *reinterpret_cast<const __half2*>(&vB));
        }
        float fA[8], fB[8];
#pragma unroll
        for (int t = 0; t < 4; ++t) {
            const float2 qA = __half22float2(aA[t]);
            const float2 qB = __half22float2(aB[t]);
            fA[2 * t] = qA.x; fA[2 * t + 1] = qA.y;
            fB[2 * t] = qB.x; fB[2 * t + 1] = qB.y;
        }
#pragma unroll
        for (int m = 2 * QUADS; m < 64; m <<= 1) {
#pragma unroll
            for (int t = 0; t < 8; ++t) fA[t] += __shfl_xor(fA[t], m, 64);
#pragma unroll
            for (int t = 0; t < 8; ++t) fB[t] += __shfl_xor(fB[t], m, 64);
        }
        if (slot == 0) {
            const float dA = rdis[rA], dB = rdis[rB];
            if constexpr (PRE) {
#pragma unroll
                for (int t = 0; t < 8; ++t) {
                    fA[t] = fmaxf(dA * fA[t] + blf[t], 0.f) * dA;
                    fB[t] = fmaxf(dB * fB[t] + blf[t], 0.f) * dB;
                }
            } else {
#pragma unroll
                for (int t = 0; t < 8; ++t) { fA[t] *= dA; fB[t] *= dB; }
            }
            *(float4*)&aggT[rA][(fq << 3)]     = make_float4(fA[0], fA[1], fA[2], fA[3]);
            *(float4*)&aggT[rA][(fq << 3) + 4] = make_float4(fA[4], fA[5], fA[6], fA[7]);
            *(float4*)&aggT[rB][(fq << 3)]     = make_float4(fB[0], fB[1], fB[2], fB[3]);
            *(float4*)&aggT[rB][(fq << 3) + 4] = make_float4(fB[4], fB[5], fB[6], fB[7]);
        }
    }
    __syncthreads();

    // phase 2: [64 x IN_W] fp32 @ [IN_W x OUT_W], W from global (L1-resident)
    constexpr int CPT = (OUT_W >= 4) ? 4 : OUT_W;
    constexpr int TXN = OUT_W / CPT;
    const int tx = tid % TXN;
    const int ty = tid / TXN;
    if (ty < TILE_R / 4) {
        float c[4][CPT];
#pragma unroll
        for (int r = 0; r < 4; ++r)
#pragma unroll
            for (int q = 0; q < CPT; ++q) c[r][q] = 0.f;

#pragma unroll 2
        for (int k4 = 0; k4 < IN_W / 4; ++k4) {
            float4 av[4];
#pragma unroll
            for (int r = 0; r < 4; ++r) av[r] = *(const float4*)&aggT[ty * 4 + r][k4 << 2];
#pragma unroll
            for (int kk = 0; kk < 4; ++kk) {
                float wv[CPT];
                if constexpr (CPT == 4) {
                    const float4 w4 = *(const float4*)(Wg + ((k4 << 2) + kk) * OUT_W + (tx << 2));
                    wv[0] = w4.x; wv[1] = w4.y; wv[2] = w4.z; wv[3] = w4.w;
                } else {
#pragma unroll
                    for (int q = 0; q < CPT; ++q)
                        wv[q] = Wg[((k4 << 2) + kk) * OUT_W + tx * CPT + q];
                }
#pragma unroll
                for (int r = 0; r < 4; ++r) {
                    const float ar = ((const float*)&av[r])[kk];
#pragma unroll
                    for (int q = 0; q < CPT; ++q) c[r][q] += ar * wv[q];
                }
            }
        }
        float bq[CPT];
#pragma unroll
        for (int q = 0; q < CPT; ++q)
            bq[q] = (HAS_BIAS && !PRE) ? bias[tx * CPT + q] : 0.f;
#pragma unroll
        for (int r = 0; r < 4; ++r) {
            const int i = tile0 + ty * 4 + r;
            if (i < NN) {
                float o[CPT];
#pragma unroll
                for (int q = 0; q < CPT; ++q) o[q] = c[r][q] + bq[q];
                if constexpr (HAS_ADD) {
#pragma unroll
                    for (int q = 0; q < CPT; ++q) o[q] += addsrc[i * OUT_W + tx * CPT + q];
                }
                if constexpr (RELU) {
#pragma unroll
                    for (int q = 0; q < CPT; ++q) o[q] = fmaxf(o[q], 0.f);
                }
                if constexpr (W32) {
                    if constexpr (CPT == 4) {
                        *(float4*)(out32 + i * OUT_W + (tx << 2)) =
                            make_float4(o[0], o[1], o[2], o[3]);
                    } else {
#pragma unroll
                        for (int q = 0; q < CPT; ++q) out32[i * OUT_W + tx * CPT + q] = o[q];
                    }
                }
                if constexpr (W16) {
                    const float d = PRE ? 1.f : dis[i];
                    if constexpr (CPT == 4) {
                        union { uint2 u; __half2 h[2]; } pk;
                        pk.h[0] = __float22half2_rn(make_float2(o[0] * d, o[1] * d));
                        pk.h[1] = __float22half2_rn(make_float2(o[2] * d, o[3] * d));
                        *(uint2*)(out16 + i * OUT_W + (tx << 2)) = pk.u;
                    } else {
#pragma unroll
                        for (int q = 0; q < CPT; ++q)
                            out16[i * OUT_W + tx * CPT + q] = __float2half(o[q] * d);
                    }
                }
            }
        }
    }
}

// ---------------- driver ----------------

extern "C" void kernel_launch(void* const* d_in, const int* in_sizes, int n_in,
                              void* d_out, int out_size, void* d_ws, size_t ws_size,
                              hipStream_t stream) {
    const float* x   = (const float*)d_in[0];
    const float* Wp  = (const float*)d_in[1];
    const float* bp  = (const float*)d_in[2];
    const float* Wr  = (const float*)d_in[3];
    const float* br  = (const float*)d_in[4];
    const float* W11 = (const float*)d_in[5];
    const float* b11 = (const float*)d_in[6];
    const float* W12 = (const float*)d_in[7];
    const float* b12 = (const float*)d_in[8];
    const float* W21 = (const float*)d_in[9];
    const float* b21 = (const float*)d_in[10];
    const float* W22 = (const float*)d_in[11];
    const float* b22 = (const float*)d_in[12];
    const float* Wh1 = (const float*)d_in[13];
    const float* bh1 = (const float*)d_in[14];
    const float* Wh2 = (const float*)d_in[15];
    const float* bh2 = (const float*)d_in[16];
    const float* Wh3 = (const float*)d_in[17];
    const float* bh3 = (const float*)d_in[18];
    const int* edge  = (const int*)d_in[19];
    const int* srcA = edge;
    const int* dstA = edge + NE;
    float* outp = (float*)d_out;

    char* p = (char*)d_ws;
    auto carve = [&](size_t bytes) {
        char* r = p;
        p += (bytes + 255) & ~(size_t)255;
        return r;
    };
    int*      cnt   = (int*)carve(NN * 4);
    int*      rptr  = (int*)carve((NN + 1) * 4);
    float*    dis   = (float*)carve(NN * 4);
    int*      sums  = (int*)carve(128 * 4);
    int*      gcnt  = (int*)carve(256 * 4);
    unsigned* bins  = (unsigned*)carve((size_t)NBUCK * BCAP * 4);
    int*      colv  = (int*)carve((size_t)(NE + NN + 256) * 4);
    float4*   xs4   = (float4*)carve((size_t)NN * 16);
    float*    ax    = (float*)carve((size_t)NN * 3 * 4);
    float*    xr    = (float*)carve((size_t)NN * 64 * 4);
    float*    bu32  = (float*)carve((size_t)NN * 64 * 4);
    float*    bw32  = (float*)carve((size_t)NN * 64 * 4);
    __half*   bt16  = (__half*)carve((size_t)NN * 64 * 2);
    __half*   bu16  = (__half*)carve((size_t)NN * 64 * 2);
    __half*   bv16  = (__half*)carve((size_t)NN * 64 * 2);
    __half*   bw16  = (__half*)carve((size_t)NN * 64 * 2);
    // head reuse (dead after main loop): z1 in bv16 (6.4MB), z2 in bw16, z3 in bu16
    __half*   z1    = bv16;
    __half*   z2    = bw16;
    __half*   z3    = bu16;

    hipMemsetAsync(gcnt, 0, 256 * 4, stream);
    const int GA = (NE + PA_EDGES - 1) / PA_EDGES;
    binA_kernel<<<GA, 256, 0, stream>>>(srcA, dstA, gcnt, bins);
    binB1_kernel<<<NBUCK, 256, 0, stream>>>(bins, gcnt, cnt);
    dis_xs_kernel<<<(NN + 255) / 256, 256, 0, stream>>>(cnt, x, dis, xs4);
    scan1_kernel<<<NCHUNK, 256, 0, stream>>>(cnt, rptr, sums);
    scan2_kernel<<<1, 128, 0, stream>>>(sums, rptr);
    scan3_kernel<<<(NN + 255) / 256, 256, 0, stream>>>(rptr, sums);
    binB2_kernel<<<NBUCK, 256, 0, stream>>>(bins, gcnt, rptr, colv);
    selffill_kernel<<<(NN + 255) / 256, 256, 0, stream>>>(rptr, cnt, colv);
    aggx_kernel<<<(NN + 255) / 256, 256, 0, stream>>>(xs4, rptr, colv, dis, ax);
    proj_kernel<<<(NN * 64 + 255) / 256, 256, 0, stream>>>(ax, Wp, bp, Wr, br, dis, bt16, xr);

    const int GB = (NN + 63) / 64;
    for (int it = 0; it < 5; ++it) {
        gcn_kernel<64, 64, false, true, false, true, true><<<GB, 256, 0, stream>>>(
            bt16, Wr, nullptr, xr, rptr, colv, dis, bu32, bu16);
        gcn_kernel<64, 64, true, false, true, false, true><<<GB, 256, 0, stream>>>(
            bu16, W11, b11, nullptr, rptr, colv, dis, nullptr, bv16);
        gcn_kernel<64, 64, true, true, true, true, true><<<GB, 256, 0, stream>>>(
            bv16, W12, b12, bu32, rptr, colv, dis, bw32, bw16);
        gcn_kernel<64, 64, true, false, true, false, true><<<GB, 256, 0, stream>>>(
            bw16, W21, b21, nullptr, rptr, colv, dis, nullptr, bv16);
        gcn_kernel<64, 64, true, true, true, false, true><<<GB, 256, 0, stream>>>(
            bv16, W22, b22, bw32, rptr, colv, dis, nullptr, bt16);
    }
    // head, multiply-first: each aggregation gathers the SMALLER width
    mmh1_kernel<<<(NN * 32 + 255) / 256, 256, 0, stream>>>(bt16, Wh1, z1);
    gcn_kernel<32, 8, false, false, false, false, true, true><<<GB, 256, 0, stream>>>(
        z1, Wh2, bh1, nullptr, rptr, colv, dis, nullptr, z2);
    gcn_kernel<8, 2, false, false, false, false, true, true><<<GB, 256, 0, stream>>>(
        z2, Wh3, bh2, nullptr, rptr, colv, dis, nullptr, z3);
    final2_kernel<<<(NN + 255) / 256, 256, 0, stream>>>(z3, rptr, colv, dis, bh3, outp);
}

// Round 11
// 1541.855 us; speedup vs baseline: 1.0314x; 1.0314x over previous
//
#include <hip/hip_runtime.h>
#include <hip/hip_fp16.h>

#define NN 100000
#define NE 1600000
#define CHUNK 1024
#define NCHUNK ((NN + CHUNK - 1) / CHUNK)
#define NBUCK 196            // dst >> 9  (512 nodes per bucket)
#define BCAP 9216            // mean 8192, sigma ~90 -> +11 sigma
#define PA_EDGES 4096

union H2x4 { uint4 u; __half2 h[4]; };
union H2x2 { uint2 u; __half2 h[2]; };

// ---------------- CSR build: two-pass LDS radix binning ----------------

__global__ __launch_bounds__(256) void binA_kernel(const int* __restrict__ src,
                                                   const int* __restrict__ dst,
                                                   int* __restrict__ gcnt,
                                                   unsigned* __restrict__ bins) {
    __shared__ int lcnt[256], lofs[256], lfil[256], gbase[256];
    __shared__ unsigned stage[PA_EDGES];
    const int tid = threadIdx.x;
    const int e0 = blockIdx.x * PA_EDGES;
    lcnt[tid] = 0; lfil[tid] = 0;
    __syncthreads();
    for (int k = 0; k < PA_EDGES / 256; ++k) {
        const int e = e0 + k * 256 + tid;
        if (e < NE) atomicAdd(&lcnt[dst[e] >> 9], 1);
    }
    __syncthreads();
    const int v = lcnt[tid];
    lofs[tid] = v;
    __syncthreads();
    for (int off = 1; off < 256; off <<= 1) {
        int xv = (tid >= off) ? lofs[tid - off] : 0;
        __syncthreads();
        lofs[tid] += xv;
        __syncthreads();
    }
    const int excl = lofs[tid] - v;
    __syncthreads();
    lofs[tid] = excl;
    if (tid < NBUCK && v > 0) gbase[tid] = atomicAdd(&gcnt[tid], v);
    else gbase[tid] = 0;
    __syncthreads();
    for (int k = 0; k < PA_EDGES / 256; ++k) {
        const int e = e0 + k * 256 + tid;
        if (e < NE) {
            const int d = dst[e];
            const int b = d >> 9;
            const int p = atomicAdd(&lfil[b], 1);
            stage[lofs[b] + p] = ((unsigned)src[e] << 9) | (unsigned)(d & 511);
        }
    }
    __syncthreads();
    const int wave = tid >> 6, lane = tid & 63;
    for (int b = wave; b < NBUCK; b += 4) {
        const int n = lcnt[b];
        const int base = gbase[b];
        const int off = lofs[b];
        for (int k = lane; k < n; k += 64) {
            const int gpos = base + k;
            if (gpos < BCAP) bins[(size_t)b * BCAP + gpos] = stage[off + k];
        }
    }
}

__global__ __launch_bounds__(256) void binB1_kernel(const unsigned* __restrict__ bins,
                                                    const int* __restrict__ gcnt,
                                                    int* __restrict__ cnt) {
    __shared__ int c512[512];
    const int b = blockIdx.x, tid = threadIdx.x;
    c512[tid] = 0; c512[256 + tid] = 0;
    __syncthreads();
    const int n = min(gcnt[b], BCAP);
    for (int k = tid; k < n; k += 256)
        atomicAdd(&c512[bins[(size_t)b * BCAP + k] & 511], 1);
    __syncthreads();
    const int i0 = b * 512 + tid;
    const int i1 = i0 + 256;
    if (i0 < NN) cnt[i0] = c512[tid];
    if (i1 < NN) cnt[i1] = c512[256 + tid];
}

__global__ __launch_bounds__(256) void binB2_kernel(const unsigned* __restrict__ bins,
                                                    const int* __restrict__ gcnt,
                                                    const int* __restrict__ rptr,
                                                    int* __restrict__ col) {
    __shared__ int fil512[512];
    __shared__ int rp_l[512];
    const int b = blockIdx.x, tid = threadIdx.x;
    fil512[tid] = 0; fil512[256 + tid] = 0;
    const int i0 = b * 512 + tid;
    const int i1 = i0 + 256;
    rp_l[tid]       = (i0 < NN) ? rptr[i0] : 0;
    rp_l[256 + tid] = (i1 < NN) ? rptr[i1] : 0;
    __syncthreads();
    const int n = min(gcnt[b], BCAP);
    for (int k = tid; k < n; k += 256) {
        const unsigned w = bins[(size_t)b * BCAP + k];
        const int dl = (int)(w & 511);
        const int s = (int)(w >> 9);
        const int p = atomicAdd(&fil512[dl], 1);
        col[rp_l[dl] + p] = s;
    }
}

// dis[i] = rsqrt(deg_i+1);  xs4 = dis-prescaled x rows, padded to float4
__global__ void dis_xs_kernel(const int* __restrict__ cnt, const float* __restrict__ x,
                              float* __restrict__ dis, float4* __restrict__ xs4) {
    int i = blockIdx.x * blockDim.x + threadIdx.x;
    if (i >= NN) return;
    float d = rsqrtf((float)(cnt[i] + 1));
    dis[i] = d;
    xs4[i] = make_float4(d * x[i * 3 + 0], d * x[i * 3 + 1], d * x[i * 3 + 2], 0.f);
}

// hierarchical exclusive scan of (cnt[i]+1)  [self-loop included in CSR]
__global__ __launch_bounds__(256) void scan1_kernel(const int* __restrict__ cnt,
                                                    int* __restrict__ row_ptr,
                                                    int* __restrict__ sums) {
    __shared__ int sdata[256];
    const int b = blockIdx.x, t = threadIdx.x;
    const int base = b * CHUNK + t * 4;
    int v0 = (base + 0 < NN) ? cnt[base + 0] + 1 : 0;
    int v1 = (base + 1 < NN) ? cnt[base + 1] + 1 : 0;
    int v2 = (base + 2 < NN) ? cnt[base + 2] + 1 : 0;
    int v3 = (base + 3 < NN) ? cnt[base + 3] + 1 : 0;
    const int s = v0 + v1 + v2 + v3;
    sdata[t] = s;
    __syncthreads();
    for (int off = 1; off < 256; off <<= 1) {
        int xv = (t >= off) ? sdata[t - off] : 0;
        __syncthreads();
        sdata[t] += xv;
        __syncthreads();
    }
    const int excl = sdata[t] - s;
    if (base + 0 < NN) row_ptr[base + 0] = excl;
    if (base + 1 < NN) row_ptr[base + 1] = excl + v0;
    if (base + 2 < NN) row_ptr[base + 2] = excl + v0 + v1;
    if (base + 3 < NN) row_ptr[base + 3] = excl + v0 + v1 + v2;
    if (t == 255) sums[b] = sdata[255];
}

__global__ __launch_bounds__(128) void scan2_kernel(int* __restrict__ sums,
                                                    int* __restrict__ row_ptr) {
    __shared__ int sd[128];
    const int t = threadIdx.x;
    const int v = (t < NCHUNK) ? sums[t] : 0;
    sd[t] = v;
    __syncthreads();
    for (int off = 1; off < 128; off <<= 1) {
        int xv = (t >= off) ? sd[t - off] : 0;
        __syncthreads();
        sd[t] += xv;
        __syncthreads();
    }
    if (t < NCHUNK) sums[t] = sd[t] - v;
    if (t == 127) row_ptr[NN] = sd[127];
}

__global__ void scan3_kernel(int* __restrict__ row_ptr, const int* __restrict__ sums) {
    int i = blockIdx.x * blockDim.x + threadIdx.x;
    if (i < NN) row_ptr[i] += sums[i >> 10];
}

__global__ void selffill_kernel(const int* __restrict__ row_ptr, const int* __restrict__ cnt,
                                int* __restrict__ col) {
    int i = blockIdx.x * blockDim.x + threadIdx.x;
    if (i >= NN) return;
    col[row_ptr[i] + cnt[i]] = i;  // self edge last in the row
}

// ax = Ahat @ x = dis_i * sum_j xs[j]   (CSR includes self loop)
__global__ void aggx_kernel(const float4* __restrict__ xs4, const int* __restrict__ row_ptr,
                            const int* __restrict__ col, const float* __restrict__ dis,
                            float* __restrict__ ax) {
    int i = blockIdx.x * blockDim.x + threadIdx.x;
    if (i >= NN) return;
    float a0 = 0.f, a1 = 0.f, a2 = 0.f;
    const int s = row_ptr[i], e = row_ptr[i + 1];
    int p = s;
    for (; p + 2 <= e; p += 2) {
        const float4 v0 = xs4[col[p]];
        const float4 v1 = xs4[col[p + 1]];
        a0 += v0.x + v1.x; a1 += v0.y + v1.y; a2 += v0.z + v1.z;
    }
    if (p < e) {
        const float4 v = xs4[col[p]];
        a0 += v.x; a1 += v.y; a2 += v.z;
    }
    const float d = dis[i];
    ax[i * 3 + 0] = d * a0; ax[i * 3 + 1] = d * a1; ax[i * 3 + 2] = d * a2;
}

// t16 = fp16(dis * relu(ax @ Wp + bp));  xr16 = fp16(ax @ Wr[64:67,:] + br)
__global__ void proj_kernel(const float* __restrict__ ax,
                            const float* __restrict__ Wp, const float* __restrict__ bp,
                            const float* __restrict__ Wr, const float* __restrict__ br,
                            const float* __restrict__ dis,
                            __half* __restrict__ t16, __half* __restrict__ xr16) {
    int g = blockIdx.x * blockDim.x + threadIdx.x;
    if (g >= NN * 64) return;
    int i = g >> 6, c = g & 63;
    float a0 = ax[i * 3 + 0], a1 = ax[i * 3 + 1], a2 = ax[i * 3 + 2];
    float tp = fmaxf(a0 * Wp[c] + a1 * Wp[64 + c] + a2 * Wp[128 + c] + bp[c], 0.f);
    t16[g] = __float2half(tp * dis[i]);
    xr16[g] = __float2half(a0 * Wr[64 * 64 + c] + a1 * Wr[65 * 64 + c] + a2 * Wr[66 * 64 + c] + br[c]);
}

// head dense: z1 = bt16 @ Wh1  (rows already dis-prescaled; multiply-first)
__global__ void mmh1_kernel(const __half* __restrict__ bt, const float* __restrict__ Wh1,
                            __half* __restrict__ z1) {
    int g = blockIdx.x * blockDim.x + threadIdx.x;
    if (g >= NN * 32) return;
    const int i = g >> 5, c = g & 31;
    const __half* row = bt + (size_t)i * 64;
    float acc = 0.f;
#pragma unroll
    for (int k4 = 0; k4 < 8; ++k4) {
        H2x4 r;
        r.u = ((const uint4*)row)[k4];
#pragma unroll
        for (int t = 0; t < 4; ++t) {
            const float2 f = __half22float2(r.h[t]);
            acc += f.x * Wh1[(k4 * 8 + 2 * t) * 32 + c];
            acc += f.y * Wh1[(k4 * 8 + 2 * t + 1) * 32 + c];
        }
    }
    z1[g] = __float2half(acc);
}

// head: per-node gather of z1 (64B rows), relu-epilogue, x Wh2 -> z2 (prescaled)
__global__ __launch_bounds__(256) void h32to8_kernel(
    const __half* __restrict__ z1, const int* __restrict__ rptr,
    const int* __restrict__ colv, const float* __restrict__ dis,
    const float* __restrict__ bh1, const float* __restrict__ Wh2,
    __half* __restrict__ z2) {
    int i = blockIdx.x * blockDim.x + threadIdx.x;
    if (i >= NN) return;
    const int s = rptr[i], e = rptr[i + 1];
    float a[32];
#pragma unroll
    for (int k = 0; k < 32; ++k) a[k] = 0.f;
    int p = s;
    for (; p + 2 <= e; p += 2) {
        const size_t j0 = (size_t)colv[p] * 32, j1 = (size_t)colv[p + 1] * 32;
        const uint4 q0 = *(const uint4*)(z1 + j0);
        const uint4 q1 = *(const uint4*)(z1 + j0 + 8);
        const uint4 q2 = *(const uint4*)(z1 + j0 + 16);
        const uint4 q3 = *(const uint4*)(z1 + j0 + 24);
        const uint4 r0 = *(const uint4*)(z1 + j1);
        const uint4 r1 = *(const uint4*)(z1 + j1 + 8);
        const uint4 r2 = *(const uint4*)(z1 + j1 + 16);
        const uint4 r3 = *(const uint4*)(z1 + j1 + 24);
        H2x4 h;
        h.u = q0;
#pragma unroll
        for (int t = 0; t < 4; ++t) { const float2 f = __half22float2(h.h[t]); a[2*t] += f.x; a[2*t+1] += f.y; }
        h.u = q1;
#pragma unroll
        for (int t = 0; t < 4; ++t) { const float2 f = __half22float2(h.h[t]); a[8+2*t] += f.x; a[9+2*t] += f.y; }
        h.u = q2;
#pragma unroll
        for (int t = 0; t < 4; ++t) { const float2 f = __half22float2(h.h[t]); a[16+2*t] += f.x; a[17+2*t] += f.y; }
        h.u = q3;
#pragma unroll
        for (int t = 0; t < 4; ++t) { const float2 f = __half22float2(h.h[t]); a[24+2*t] += f.x; a[25+2*t] += f.y; }
        h.u = r0;
#pragma unroll
        for (int t = 0; t < 4; ++t) { const float2 f = __half22float2(h.h[t]); a[2*t] += f.x; a[2*t+1] += f.y; }
        h.u = r1;
#pragma unroll
        for (int t = 0; t < 4; ++t) { const float2 f = __half22float2(h.h[t]); a[8+2*t] += f.x; a[9+2*t] += f.y; }
        h.u = r2;
#pragma unroll
        for (int t = 0; t < 4; ++t) { const float2 f = __half22float2(h.h[t]); a[16+2*t] += f.x; a[17+2*t] += f.y; }
        h.u = r3;
#pragma unroll
        for (int t = 0; t < 4; ++t) { const float2 f = __half22float2(h.h[t]); a[24+2*t] += f.x; a[25+2*t] += f.y; }
    }
    if (p < e) {
        const size_t j0 = (size_t)colv[p] * 32;
        const uint4 q0 = *(const uint4*)(z1 + j0);
        const uint4 q1 = *(const uint4*)(z1 + j0 + 8);
        const uint4 q2 = *(const uint4*)(z1 + j0 + 16);
        const uint4 q3 = *(const uint4*)(z1 + j0 + 24);
        H2x4 h;
        h.u = q0;
#pragma unroll
        for (int t = 0; t < 4; ++t) { const float2 f = __half22float2(h.h[t]); a[2*t] += f.x; a[2*t+1] += f.y; }
        h.u = q1;
#pragma unroll
        for (int t = 0; t < 4; ++t) { const float2 f = __half22float2(h.h[t]); a[8+2*t] += f.x; a[9+2*t] += f.y; }
        h.u = q2;
#pragma unroll
        for (int t = 0; t < 4; ++t) { const float2 f = __half22float2(h.h[t]); a[16+2*t] += f.x; a[17+2*t] += f.y; }
        h.u = q3;
#pragma unroll
        for (int t = 0; t < 4; ++t) { const float2 f = __half22float2(h.h[t]); a[24+2*t] += f.x; a[25+2*t] += f.y; }
    }
    const float d = dis[i];
#pragma unroll
    for (int k = 0; k < 32; ++k) a[k] = fmaxf(d * a[k] + bh1[k], 0.f) * d;
    float o[8];
#pragma unroll
    for (int c = 0; c < 8; ++c) o[c] = 0.f;
#pragma unroll
    for (int k = 0; k < 32; ++k)
#pragma unroll
        for (int c = 0; c < 8; ++c) o[c] += a[k] * Wh2[k * 8 + c];
    H2x4 pk;
#pragma unroll
    for (int t = 0; t < 4; ++t) pk.h[t] = __float22half2_rn(make_float2(o[2 * t], o[2 * t + 1]));
    *(uint4*)(z2 + (size_t)i * 8) = pk.u;
}

// head: per-node gather of z2 (16B rows), relu-epilogue, x Wh3 -> z3 (prescaled)
__global__ __launch_bounds__(256) void h8to2_kernel(
    const __half* __restrict__ z2, const int* __restrict__ rptr,
    const int* __restrict__ colv, const float* __restrict__ dis,
    const float* __restrict__ bh2, const float* __restrict__ Wh3,
    __half* __restrict__ z3) {
    int i = blockIdx.x * blockDim.x + threadIdx.x;
    if (i >= NN) return;
    const int s = rptr[i], e = rptr[i + 1];
    float a[8];
#pragma unroll
    for (int k = 0; k < 8; ++k) a[k] = 0.f;
    int p = s;
    for (; p + 4 <= e; p += 4) {
        const uint4 q0 = *(const uint4*)(z2 + (size_t)colv[p] * 8);
        const uint4 q1 = *(const uint4*)(z2 + (size_t)colv[p + 1] * 8);
        const uint4 q2 = *(const uint4*)(z2 + (size_t)colv[p + 2] * 8);
        const uint4 q3 = *(const uint4*)(z2 + (size_t)colv[p + 3] * 8);
        H2x4 h;
        h.u = q0;
#pragma unroll
        for (int t = 0; t < 4; ++t) { const float2 f = __half22float2(h.h[t]); a[2*t] += f.x; a[2*t+1] += f.y; }
        h.u = q1;
#pragma unroll
        for (int t = 0; t < 4; ++t) { const float2 f = __half22float2(h.h[t]); a[2*t] += f.x; a[2*t+1] += f.y; }
        h.u = q2;
#pragma unroll
        for (int t = 0; t < 4; ++t) { const float2 f = __half22float2(h.h[t]); a[2*t] += f.x; a[2*t+1] += f.y; }
        h.u = q3;
#pragma unroll
        for (int t = 0; t < 4; ++t) { const float2 f = __half22float2(h.h[t]); a[2*t] += f.x; a[2*t+1] += f.y; }
    }
    for (; p < e; ++p) {
        const uint4 q0 = *(const uint4*)(z2 + (size_t)colv[p] * 8);
        H2x4 h;
        h.u = q0;
#pragma unroll
        for (int t = 0; t < 4; ++t) { const float2 f = __half22float2(h.h[t]); a[2*t] += f.x; a[2*t+1] += f.y; }
    }
    const float d = dis[i];
    float o0 = 0.f, o1 = 0.f;
#pragma unroll
    for (int k = 0; k < 8; ++k) {
        const float ak = fmaxf(d * a[k] + bh2[k], 0.f) * d;
        o0 += ak * Wh3[k * 2 + 0];
        o1 += ak * Wh3[k * 2 + 1];
    }
    ((__half2*)z3)[i] = __float22half2_rn(make_float2(o0, o1));
}

// head final: out = dis_i * sum_j z3[j] + bh3   (4B rows, L2-resident)
__global__ void final2_kernel(const __half* __restrict__ z3, const int* __restrict__ rptr,
                              const int* __restrict__ col, const float* __restrict__ dis,
                              const float* __restrict__ bh3, float* __restrict__ out) {
    int i = blockIdx.x * blockDim.x + threadIdx.x;
    if (i >= NN) return;
    const int s = rptr[i], e = rptr[i + 1];
    float a0 = 0.f, a1 = 0.f;
    int p = s;
    for (; p + 2 <= e; p += 2) {
        const __half2 h0 = ((const __half2*)z3)[col[p]];
        const __half2 h1 = ((const __half2*)z3)[col[p + 1]];
        const float2 f0 = __half22float2(h0);
        const float2 f1 = __half22float2(h1);
        a0 += f0.x + f1.x; a1 += f0.y + f1.y;
    }
    if (p < e) {
        const float2 f = __half22float2(((const __half2*)z3)[col[p]]);
        a0 += f.x; a1 += f.y;
    }
    const float d = dis[i];
    out[2 * i]     = d * a0 + bh3[0];
    out[2 * i + 1] = d * a1 + bh3[1];
}

// ---------------- fused GCN (64-wide main layers) ----------------
// h16 rows fp16, pre-scaled by dis[j]. agg_i = dis_i * sum_{j in row} h16[j].
// Phase 1: two rows jointly, straight-line, named vars only (R7 lesson).
// Phase 2: [64 x 64] fp32 @ W; addsrc (residual) is fp16; outputs:
//   WRAW -> unscaled fp16 (residual source), W16 -> dis-prescaled fp16 (gather input)

template <int IN_W, int OUT_W, bool RELU, bool HAS_ADD, bool HAS_BIAS, bool WRAW, bool W16>
__global__ __launch_bounds__(256, 4) void gcn_kernel(
    const __half* __restrict__ h16, const float* __restrict__ Wg,
    const float* __restrict__ bias, const __half* __restrict__ addsrc,
    const int* __restrict__ row_ptr, const int* __restrict__ colv,
    const float* __restrict__ dis,
    __half* __restrict__ outraw, __half* __restrict__ out16) {
    constexpr int TILE_R = 64;
    constexpr int QUADS = IN_W / 8;      // lanes per row (16B = 8 halves each)
    constexpr int SLOTS = 64 / QUADS;    // rows gathered per wave instruction
    constexpr int STR = IN_W + 4;
    __shared__ __align__(16) float aggT[TILE_R][STR];
    __shared__ int rp[TILE_R + 1];
    __shared__ float rdis[TILE_R];

    const int tid = threadIdx.x;
    const int tile0 = blockIdx.x * TILE_R;

    if (tid <= TILE_R) rp[tid] = row_ptr[min(tile0 + tid, NN)];
    if (tid < TILE_R) {
        const int i = tile0 + tid;
        rdis[tid] = (i < NN) ? dis[i] : 0.f;
    }
    __syncthreads();

    const int wave = tid >> 6;
    const int lane = tid & 63;
    const int fq = lane & (QUADS - 1);
    const int slot = lane / QUADS;
    const int rbase = wave << 4;
    const size_t fqo = (size_t)(fq << 3);

    const __half2 ONE2 = __float2half2_rn(1.0f);
    const __half2 ZERO2 = __float2half2_rn(0.0f);

    for (int hr = 0; hr < 8; ++hr) {
        const int rA = rbase + 2 * hr;
        const int rB = rA + 1;
        const int sA = __builtin_amdgcn_readfirstlane(rp[rA]);
        const int eA = __builtin_amdgcn_readfirstlane(rp[rA + 1]);
        const int sB = eA;
        const int eB = __builtin_amdgcn_readfirstlane(rp[rB + 1]);
        const int lastA = eA - 1, lastB = eB - 1;
        const int pA = sA + slot, pB = sB + slot;

        const int jA0 = colv[min(pA, lastA)];
        const int jA1 = colv[min(pA + SLOTS, lastA)];
        const int jA2 = colv[min(pA + 2 * SLOTS, lastA)];
        const int jA3 = colv[min(pA + 3 * SLOTS, lastA)];
        const int jB0 = colv[min(pB, lastB)];
        const int jB1 = colv[min(pB + SLOTS, lastB)];
        const int jB2 = colv[min(pB + 2 * SLOTS, lastB)];
        const int jB3 = colv[min(pB + 3 * SLOTS, lastB)];
        const uint4 gA0 = *(const uint4*)(h16 + (size_t)jA0 * IN_W + fqo);
        const uint4 gA1 = *(const uint4*)(h16 + (size_t)jA1 * IN_W + fqo);
        const uint4 gA2 = *(const uint4*)(h16 + (size_t)jA2 * IN_W + fqo);
        const uint4 gA3 = *(const uint4*)(h16 + (size_t)jA3 * IN_W + fqo);
        const uint4 gB0 = *(const uint4*)(h16 + (size_t)jB0 * IN_W + fqo);
        const uint4 gB1 = *(const uint4*)(h16 + (size_t)jB1 * IN_W + fqo);
        const uint4 gB2 = *(const uint4*)(h16 + (size_t)jB2 * IN_W + fqo);
        const uint4 gB3 = *(const uint4*)(h16 + (size_t)jB3 * IN_W + fqo);

        __half2 aA[4] = {ZERO2, ZERO2, ZERO2, ZERO2};
        __half2 aB[4] = {ZERO2, ZERO2, ZERO2, ZERO2};
        {
            H2x4 hh;
            const __half2 mA0 = (pA < eA) ? ONE2 : ZERO2;
            const __half2 mA1 = (pA + SLOTS < eA) ? ONE2 : ZERO2;
            const __half2 mA2 = (pA + 2 * SLOTS < eA) ? ONE2 : ZERO2;
            const __half2 mA3 = (pA + 3 * SLOTS < eA) ? ONE2 : ZERO2;
            const __half2 mB0 = (pB < eB) ? ONE2 : ZERO2;
            const __half2 mB1 = (pB + SLOTS < eB) ? ONE2 : ZERO2;
            const __half2 mB2 = (pB + 2 * SLOTS < eB) ? ONE2 : ZERO2;
            const __half2 mB3 = (pB + 3 * SLOTS < eB) ? ONE2 : ZERO2;
            hh.u = gA0;
#pragma unroll
            for (int t = 0; t < 4; ++t) aA[t] = __hfma2(hh.h[t], mA0, aA[t]);
            hh.u = gA1;
#pragma unroll
            for (int t = 0; t < 4; ++t) aA[t] = __hfma2(hh.h[t], mA1, aA[t]);
            hh.u = gA2;
#pragma unroll
            for (int t = 0; t < 4; ++t) aA[t] = __hfma2(hh.h[t], mA2, aA[t]);
            hh.u = gA3;
#pragma unroll
            for (int t = 0; t < 4; ++t) aA[t] = __hfma2(hh.h[t], mA3, aA[t]);
            hh.u = gB0;
#pragma unroll
            for (int t = 0; t < 4; ++t) aB[t] = __hfma2(hh.h[t], mB0, aB[t]);
            hh.u = gB1;
#pragma unroll
            for (int t = 0; t < 4; ++t) aB[t] = __hfma2(hh.h[t], mB1, aB[t]);
            hh.u = gB2;
#pragma unroll
            for (int t = 0; t < 4; ++t) aB[t] = __hfma2(hh.h[t], mB2, aB[t]);
            hh.u = gB3;
#pragma unroll
            for (int t = 0; t < 4; ++t) aB[t] = __hfma2(hh.h[t], mB3, aB[t]);
        }
        if (eA - sA > 4 * SLOTS) {
            H2x4 hh;
            for (int p = pA + 4 * SLOTS; p < eA; p += SLOTS) {
                hh.u = *(const uint4*)(h16 + (size_t)colv[p] * IN_W + fqo);
#pragma unroll
                for (int t = 0; t < 4; ++t) aA[t] = __hadd2(aA[t], hh.h[t]);
            }
        }
        if (eB - sB > 4 * SLOTS) {
            H2x4 hh;
            for (int p = pB + 4 * SLOTS; p < eB; p += SLOTS) {
                hh.u = *(const uint4*)(h16 + (size_t)colv[p] * IN_W + fqo);
#pragma unroll
                for (int t = 0; t < 4; ++t) aB[t] = __hadd2(aB[t], hh.h[t]);
            }
        }
#pragma unroll
        for (int t = 0; t < 4; ++t) {
            int vA = __shfl_xor(*reinterpret_cast<const int*>(&aA[t]), QUADS, 64);
            int vB = __shfl_xor(*reinterpret_cast<const int*>(&aB[t]), QUADS, 64);
            aA[t] = __hadd2(aA[t], *reinterpret_cast<const __half2*>(&vA));
            aB[t] = __hadd2(aB[t], *reinterpret_cast<const __half2*>(&vB));
        }
        float fA[8], fB[8];
#pragma unroll
        for (int t = 0; t < 4; ++t) {
            const float2 qA = __half22float2(aA[t]);
            const float2 qB = __half22float2(aB[t]);
            fA[2 * t] = qA.x; fA[2 * t + 1] = qA.y;
            fB[2 * t] = qB.x; fB[2 * t + 1] = qB.y;
        }
#pragma unroll
        for (int m = 2 * QUADS; m < 64; m <<= 1) {
#pragma unroll
            for (int t = 0; t < 8; ++t) fA[t] += __shfl_xor(fA[t], m, 64);
#pragma unroll
            for (int t = 0; t < 8; ++t) fB[t] += __shfl_xor(fB[t], m, 64);
        }
        if (slot == 0) {
            const float dA = rdis[rA], dB = rdis[rB];
#pragma unroll
            for (int t = 0; t < 8; ++t) { fA[t] *= dA; fB[t] *= dB; }
            *(float4*)&aggT[rA][(fq << 3)]     = make_float4(fA[0], fA[1], fA[2], fA[3]);
            *(float4*)&aggT[rA][(fq << 3) + 4] = make_float4(fA[4], fA[5], fA[6], fA[7]);
            *(float4*)&aggT[rB][(fq << 3)]     = make_float4(fB[0], fB[1], fB[2], fB[3]);
            *(float4*)&aggT[rB][(fq << 3) + 4] = make_float4(fB[4], fB[5], fB[6], fB[7]);
        }
    }
    __syncthreads();

    // phase 2: [64 x IN_W] fp32 @ [IN_W x OUT_W], W from global (L1-resident)
    constexpr int CPT = 4;
    constexpr int TXN = OUT_W / CPT;
    const int tx = tid % TXN;
    const int ty = tid / TXN;
    if (ty < TILE_R / 4) {
        float c[4][CPT];
#pragma unroll
        for (int r = 0; r < 4; ++r)
#pragma unroll
            for (int q = 0; q < CPT; ++q) c[r][q] = 0.f;

#pragma unroll 2
        for (int k4 = 0; k4 < IN_W / 4; ++k4) {
            float4 av[4];
#pragma unroll
            for (int r = 0; r < 4; ++r) av[r] = *(const float4*)&aggT[ty * 4 + r][k4 << 2];
#pragma unroll
            for (int kk = 0; kk < 4; ++kk) {
                const float4 w4 = *(const float4*)(Wg + ((k4 << 2) + kk) * OUT_W + (tx << 2));
                float wv[CPT] = {w4.x, w4.y, w4.z, w4.w};
#pragma unroll
                for (int r = 0; r < 4; ++r) {
                    const float ar = ((const float*)&av[r])[kk];
#pragma unroll
                    for (int q = 0; q < CPT; ++q) c[r][q] += ar * wv[q];
                }
            }
        }
        float bq[CPT];
#pragma unroll
        for (int q = 0; q < CPT; ++q) bq[q] = HAS_BIAS ? bias[tx * CPT + q] : 0.f;
#pragma unroll
        for (int r = 0; r < 4; ++r) {
            const int i = tile0 + ty * 4 + r;
            if (i < NN) {
                float o[CPT];
#pragma unroll
                for (int q = 0; q < CPT; ++q) o[q] = c[r][q] + bq[q];
                if constexpr (HAS_ADD) {
                    H2x2 ad;
                    ad.u = *(const uint2*)(addsrc + (size_t)i * OUT_W + (tx << 2));
#pragma unroll
                    for (int t = 0; t < 2; ++t) {
                        const float2 f = __half22float2(ad.h[t]);
                        o[2 * t] += f.x; o[2 * t + 1] += f.y;
                    }
                }
                if constexpr (RELU) {
#pragma unroll
                    for (int q = 0; q < CPT; ++q) o[q] = fmaxf(o[q], 0.f);
                }
                if constexpr (WRAW) {
                    H2x2 pk;
                    pk.h[0] = __float22half2_rn(make_float2(o[0], o[1]));
                    pk.h[1] = __float22half2_rn(make_float2(o[2], o[3]));
                    *(uint2*)(outraw + (size_t)i * OUT_W + (tx << 2)) = pk.u;
                }
                if constexpr (W16) {
                    const float d = dis[i];
                    H2x2 pk;
                    pk.h[0] = __float22half2_rn(make_float2(o[0] * d, o[1] * d));
                    pk.h[1] = __float22half2_rn(make_float2(o[2] * d, o[3] * d));
                    *(uint2*)(out16 + (size_t)i * OUT_W + (tx << 2)) = pk.u;
                }
            }
        }
    }
}

// ---------------- driver ----------------

extern "C" void kernel_launch(void* const* d_in, const int* in_sizes, int n_in,
                              void* d_out, int out_size, void* d_ws, size_t ws_size,
                              hipStream_t stream) {
    const float* x   = (const float*)d_in[0];
    const float* Wp  = (const float*)d_in[1];
    const float* bp  = (const float*)d_in[2];
    const float* Wr  = (const float*)d_in[3];
    const float* br  = (const float*)d_in[4];
    const float* W11 = (const float*)d_in[5];
    const float* b11 = (const float*)d_in[6];
    const float* W12 = (const float*)d_in[7];
    const float* b12 = (const float*)d_in[8];
    const float* W21 = (const float*)d_in[9];
    const float* b21 = (const float*)d_in[10];
    const float* W22 = (const float*)d_in[11];
    const float* b22 = (const float*)d_in[12];
    const float* Wh1 = (const float*)d_in[13];
    const float* bh1 = (const float*)d_in[14];
    const float* Wh2 = (const float*)d_in[15];
    const float* bh2 = (const float*)d_in[16];
    const float* Wh3 = (const float*)d_in[17];
    const float* bh3 = (const float*)d_in[18];
    const int* edge  = (const int*)d_in[19];
    const int* srcA = edge;
    const int* dstA = edge + NE;
    float* outp = (float*)d_out;

    char* p = (char*)d_ws;
    auto carve = [&](size_t bytes) {
        char* r = p;
        p += (bytes + 255) & ~(size_t)255;
        return r;
    };
    int*      cnt   = (int*)carve(NN * 4);
    int*      rptr  = (int*)carve((NN + 1) * 4);
    float*    dis   = (float*)carve(NN * 4);
    int*      sums  = (int*)carve(128 * 4);
    int*      gcnt  = (int*)carve(256 * 4);
    unsigned* bins  = (unsigned*)carve((size_t)NBUCK * BCAP * 4);
    int*      colv  = (int*)carve((size_t)(NE + NN + 256) * 4);
    float4*   xs4   = (float4*)carve((size_t)NN * 16);
    float*    ax    = (float*)carve((size_t)NN * 3 * 4);
    __half*   xr16  = (__half*)carve((size_t)NN * 64 * 2);
    __half*   bu16b = (__half*)carve((size_t)NN * 64 * 2);
    __half*   bw16b = (__half*)carve((size_t)NN * 64 * 2);
    __half*   bt16  = (__half*)carve((size_t)NN * 64 * 2);
    __half*   bu16  = (__half*)carve((size_t)NN * 64 * 2);
    __half*   bv16  = (__half*)carve((size_t)NN * 64 * 2);
    __half*   bw16  = (__half*)carve((size_t)NN * 64 * 2);
    // head reuse (dead after main loop)
    __half*   z1    = bv16;   // NN x 32
    __half*   z2    = bw16;   // NN x 8
    __half*   z3    = bu16;   // NN x 2

    hipMemsetAsync(gcnt, 0, 256 * 4, stream);
    const int GA = (NE + PA_EDGES - 1) / PA_EDGES;
    binA_kernel<<<GA, 256, 0, stream>>>(srcA, dstA, gcnt, bins);
    binB1_kernel<<<NBUCK, 256, 0, stream>>>(bins, gcnt, cnt);
    dis_xs_kernel<<<(NN + 255) / 256, 256, 0, stream>>>(cnt, x, dis, xs4);
    scan1_kernel<<<NCHUNK, 256, 0, stream>>>(cnt, rptr, sums);
    scan2_kernel<<<1, 128, 0, stream>>>(sums, rptr);
    scan3_kernel<<<(NN + 255) / 256, 256, 0, stream>>>(rptr, sums);
    binB2_kernel<<<NBUCK, 256, 0, stream>>>(bins, gcnt, rptr, colv);
    selffill_kernel<<<(NN + 255) / 256, 256, 0, stream>>>(rptr, cnt, colv);
    aggx_kernel<<<(NN + 255) / 256, 256, 0, stream>>>(xs4, rptr, colv, dis, ax);
    proj_kernel<<<(NN * 64 + 255) / 256, 256, 0, stream>>>(ax, Wp, bp, Wr, br, dis, bt16, xr16);

    const int GB = (NN + 63) / 64;
    for (int it = 0; it < 5; ++it) {
        // recall: o = agg@Wr_top + xr ; raw fp16 (residual src) + scaled fp16
        gcn_kernel<64, 64, false, true, false, true, true><<<GB, 256, 0, stream>>>(
            bt16, Wr, nullptr, xr16, rptr, colv, dis, bu16b, bu16);
        // b1a: relu(gcn(bu, W11, b11))
        gcn_kernel<64, 64, true, false, true, false, true><<<GB, 256, 0, stream>>>(
            bu16, W11, b11, nullptr, rptr, colv, dis, nullptr, bv16);
        // b1b: relu(gcn(bv, W12, b12) + bu)  -> raw + scaled
        gcn_kernel<64, 64, true, true, true, true, true><<<GB, 256, 0, stream>>>(
            bv16, W12, b12, bu16b, rptr, colv, dis, bw16b, bw16);
        // b2a
        gcn_kernel<64, 64, true, false, true, false, true><<<GB, 256, 0, stream>>>(
            bw16, W21, b21, nullptr, rptr, colv, dis, nullptr, bv16);
        // b2b: relu(gcn(bv, W22, b22) + bw) -> scaled only
        gcn_kernel<64, 64, true, true, true, false, true><<<GB, 256, 0, stream>>>(
            bv16, W22, b22, bw16b, rptr, colv, dis, nullptr, bt16);
    }
    // head, multiply-first, per-node narrow kernels
    mmh1_kernel<<<(NN * 32 + 255) / 256, 256, 0, stream>>>(bt16, Wh1, z1);
    h32to8_kernel<<<(NN + 255) / 256, 256, 0, stream>>>(z1, rptr, colv, dis, bh1, Wh2, z2);
    h8to2_kernel<<<(NN + 255) / 256, 256, 0, stream>>>(z2, rptr, colv, dis, bh2, Wh3, z3);
    final2_kernel<<<(NN + 255) / 256, 256, 0, stream>>>(z3, rptr, colv, dis, bh3, outp);
}

// Round 12
// 1523.499 us; speedup vs baseline: 1.0438x; 1.0120x over previous
//
#include <hip/hip_runtime.h>
#include <hip/hip_fp16.h>

#define NN 100000
#define NE 1600000
#define CHUNK 1024
#define NCHUNK ((NN + CHUNK - 1) / CHUNK)
#define NBUCK 196            // dst >> 9  (512 nodes per bucket)
#define BCAP 9216            // mean 8192, sigma ~90 -> +11 sigma
#define PA_EDGES 4096

union H2x4 { uint4 u; __half2 h[4]; };
union H2x2 { uint2 u; __half2 h[2]; };

// ---------------- CSR build: two-pass LDS radix binning ----------------

__global__ __launch_bounds__(256) void binA_kernel(const int* __restrict__ src,
                                                   const int* __restrict__ dst,
                                                   int* __restrict__ gcnt,
                                                   unsigned* __restrict__ bins) {
    __shared__ int lcnt[256], lofs[256], lfil[256], gbase[256];
    __shared__ unsigned stage[PA_EDGES];
    const int tid = threadIdx.x;
    const int e0 = blockIdx.x * PA_EDGES;
    lcnt[tid] = 0; lfil[tid] = 0;
    __syncthreads();
    for (int k = 0; k < PA_EDGES / 256; ++k) {
        const int e = e0 + k * 256 + tid;
        if (e < NE) atomicAdd(&lcnt[dst[e] >> 9], 1);
    }
    __syncthreads();
    const int v = lcnt[tid];
    lofs[tid] = v;
    __syncthreads();
    for (int off = 1; off < 256; off <<= 1) {
        int xv = (tid >= off) ? lofs[tid - off] : 0;
        __syncthreads();
        lofs[tid] += xv;
        __syncthreads();
    }
    const int excl = lofs[tid] - v;
    __syncthreads();
    lofs[tid] = excl;
    if (tid < NBUCK && v > 0) gbase[tid] = atomicAdd(&gcnt[tid], v);
    else gbase[tid] = 0;
    __syncthreads();
    for (int k = 0; k < PA_EDGES / 256; ++k) {
        const int e = e0 + k * 256 + tid;
        if (e < NE) {
            const int d = dst[e];
            const int b = d >> 9;
            const int p = atomicAdd(&lfil[b], 1);
            stage[lofs[b] + p] = ((unsigned)src[e] << 9) | (unsigned)(d & 511);
        }
    }
    __syncthreads();
    const int wave = tid >> 6, lane = tid & 63;
    for (int b = wave; b < NBUCK; b += 4) {
        const int n = lcnt[b];
        const int base = gbase[b];
        const int off = lofs[b];
        for (int k = lane; k < n; k += 64) {
            const int gpos = base + k;
            if (gpos < BCAP) bins[(size_t)b * BCAP + gpos] = stage[off + k];
        }
    }
}

__global__ __launch_bounds__(256) void binB1_kernel(const unsigned* __restrict__ bins,
                                                    const int* __restrict__ gcnt,
                                                    int* __restrict__ cnt) {
    __shared__ int c512[512];
    const int b = blockIdx.x, tid = threadIdx.x;
    c512[tid] = 0; c512[256 + tid] = 0;
    __syncthreads();
    const int n = min(gcnt[b], BCAP);
    for (int k = tid; k < n; k += 256)
        atomicAdd(&c512[bins[(size_t)b * BCAP + k] & 511], 1);
    __syncthreads();
    const int i0 = b * 512 + tid;
    const int i1 = i0 + 256;
    if (i0 < NN) cnt[i0] = c512[tid];
    if (i1 < NN) cnt[i1] = c512[256 + tid];
}

__global__ __launch_bounds__(256) void binB2_kernel(const unsigned* __restrict__ bins,
                                                    const int* __restrict__ gcnt,
                                                    const int* __restrict__ rptr,
                                                    int* __restrict__ col) {
    __shared__ int fil512[512];
    __shared__ int rp_l[512];
    const int b = blockIdx.x, tid = threadIdx.x;
    fil512[tid] = 0; fil512[256 + tid] = 0;
    const int i0 = b * 512 + tid;
    const int i1 = i0 + 256;
    rp_l[tid]       = (i0 < NN) ? rptr[i0] : 0;
    rp_l[256 + tid] = (i1 < NN) ? rptr[i1] : 0;
    __syncthreads();
    const int n = min(gcnt[b], BCAP);
    for (int k = tid; k < n; k += 256) {
        const unsigned w = bins[(size_t)b * BCAP + k];
        const int dl = (int)(w & 511);
        const int s = (int)(w >> 9);
        const int p = atomicAdd(&fil512[dl], 1);
        col[rp_l[dl] + p] = s;
    }
}

// dis[i] = rsqrt(deg_i+1);  xs4 = dis-prescaled x rows, padded to float4
__global__ void dis_xs_kernel(const int* __restrict__ cnt, const float* __restrict__ x,
                              float* __restrict__ dis, float4* __restrict__ xs4) {
    int i = blockIdx.x * blockDim.x + threadIdx.x;
    if (i >= NN) return;
    float d = rsqrtf((float)(cnt[i] + 1));
    dis[i] = d;
    xs4[i] = make_float4(d * x[i * 3 + 0], d * x[i * 3 + 1], d * x[i * 3 + 2], 0.f);
}

// hierarchical exclusive scan of (cnt[i]+1)  [self-loop included in CSR]
__global__ __launch_bounds__(256) void scan1_kernel(const int* __restrict__ cnt,
                                                    int* __restrict__ row_ptr,
                                                    int* __restrict__ sums) {
    __shared__ int sdata[256];
    const int b = blockIdx.x, t = threadIdx.x;
    const int base = b * CHUNK + t * 4;
    int v0 = (base + 0 < NN) ? cnt[base + 0] + 1 : 0;
    int v1 = (base + 1 < NN) ? cnt[base + 1] + 1 : 0;
    int v2 = (base + 2 < NN) ? cnt[base + 2] + 1 : 0;
    int v3 = (base + 3 < NN) ? cnt[base + 3] + 1 : 0;
    const int s = v0 + v1 + v2 + v3;
    sdata[t] = s;
    __syncthreads();
    for (int off = 1; off < 256; off <<= 1) {
        int xv = (t >= off) ? sdata[t - off] : 0;
        __syncthreads();
        sdata[t] += xv;
        __syncthreads();
    }
    const int excl = sdata[t] - s;
    if (base + 0 < NN) row_ptr[base + 0] = excl;
    if (base + 1 < NN) row_ptr[base + 1] = excl + v0;
    if (base + 2 < NN) row_ptr[base + 2] = excl + v0 + v1;
    if (base + 3 < NN) row_ptr[base + 3] = excl + v0 + v1 + v2;
    if (t == 255) sums[b] = sdata[255];
}

__global__ __launch_bounds__(128) void scan2_kernel(int* __restrict__ sums,
                                                    int* __restrict__ row_ptr) {
    __shared__ int sd[128];
    const int t = threadIdx.x;
    const int v = (t < NCHUNK) ? sums[t] : 0;
    sd[t] = v;
    __syncthreads();
    for (int off = 1; off < 128; off <<= 1) {
        int xv = (t >= off) ? sd[t - off] : 0;
        __syncthreads();
        sd[t] += xv;
        __syncthreads();
    }
    if (t < NCHUNK) sums[t] = sd[t] - v;
    if (t == 127) row_ptr[NN] = sd[127];
}

__global__ void scan3_kernel(int* __restrict__ row_ptr, const int* __restrict__ sums) {
    int i = blockIdx.x * blockDim.x + threadIdx.x;
    if (i < NN) row_ptr[i] += sums[i >> 10];
}

__global__ void selffill_kernel(const int* __restrict__ row_ptr, const int* __restrict__ cnt,
                                int* __restrict__ col) {
    int i = blockIdx.x * blockDim.x + threadIdx.x;
    if (i >= NN) return;
    col[row_ptr[i] + cnt[i]] = i;  // self edge last in the row
}

// ax = Ahat @ x = dis_i * sum_j xs[j]   (CSR includes self loop)
__global__ void aggx_kernel(const float4* __restrict__ xs4, const int* __restrict__ row_ptr,
                            const int* __restrict__ col, const float* __restrict__ dis,
                            float* __restrict__ ax) {
    int i = blockIdx.x * blockDim.x + threadIdx.x;
    if (i >= NN) return;
    float a0 = 0.f, a1 = 0.f, a2 = 0.f;
    const int s = row_ptr[i], e = row_ptr[i + 1];
    int p = s;
    for (; p + 2 <= e; p += 2) {
        const float4 v0 = xs4[col[p]];
        const float4 v1 = xs4[col[p + 1]];
        a0 += v0.x + v1.x; a1 += v0.y + v1.y; a2 += v0.z + v1.z;
    }
    if (p < e) {
        const float4 v = xs4[col[p]];
        a0 += v.x; a1 += v.y; a2 += v.z;
    }
    const float d = dis[i];
    ax[i * 3 + 0] = d * a0; ax[i * 3 + 1] = d * a1; ax[i * 3 + 2] = d * a2;
}

// t16 = fp16(dis * relu(ax @ Wp + bp));  xr16 = fp16(ax @ Wr[64:67,:] + br)
__global__ void proj_kernel(const float* __restrict__ ax,
                            const float* __restrict__ Wp, const float* __restrict__ bp,
                            const float* __restrict__ Wr, const float* __restrict__ br,
                            const float* __restrict__ dis,
                            __half* __restrict__ t16, __half* __restrict__ xr16) {
    int g = blockIdx.x * blockDim.x + threadIdx.x;
    if (g >= NN * 64) return;
    int i = g >> 6, c = g & 63;
    float a0 = ax[i * 3 + 0], a1 = ax[i * 3 + 1], a2 = ax[i * 3 + 2];
    float tp = fmaxf(a0 * Wp[c] + a1 * Wp[64 + c] + a2 * Wp[128 + c] + bp[c], 0.f);
    t16[g] = __float2half(tp * dis[i]);
    xr16[g] = __float2half(a0 * Wr[64 * 64 + c] + a1 * Wr[65 * 64 + c] + a2 * Wr[66 * 64 + c] + br[c]);
}

// head dense: z1 = bt16 @ Wh1  (rows already dis-prescaled; multiply-first)
__global__ void mmh1_kernel(const __half* __restrict__ bt, const float* __restrict__ Wh1,
                            __half* __restrict__ z1) {
    int g = blockIdx.x * blockDim.x + threadIdx.x;
    if (g >= NN * 32) return;
    const int i = g >> 5, c = g & 31;
    const __half* row = bt + (size_t)i * 64;
    float acc = 0.f;
#pragma unroll
    for (int k4 = 0; k4 < 8; ++k4) {
        H2x4 r;
        r.u = ((const uint4*)row)[k4];
#pragma unroll
        for (int t = 0; t < 4; ++t) {
            const float2 f = __half22float2(r.h[t]);
            acc += f.x * Wh1[(k4 * 8 + 2 * t) * 32 + c];
            acc += f.y * Wh1[(k4 * 8 + 2 * t + 1) * 32 + c];
        }
    }
    z1[g] = __float2half(acc);
}

// head: per-node gather of z1 (64B rows), relu-epilogue, x Wh2 -> z2 (prescaled)
__global__ __launch_bounds__(256) void h32to8_kernel(
    const __half* __restrict__ z1, const int* __restrict__ rptr,
    const int* __restrict__ colv, const float* __restrict__ dis,
    const float* __restrict__ bh1, const float* __restrict__ Wh2,
    __half* __restrict__ z2) {
    int i = blockIdx.x * blockDim.x + threadIdx.x;
    if (i >= NN) return;
    const int s = rptr[i], e = rptr[i + 1];
    float a[32];
#pragma unroll
    for (int k = 0; k < 32; ++k) a[k] = 0.f;
    int p = s;
    for (; p + 2 <= e; p += 2) {
        const size_t j0 = (size_t)colv[p] * 32, j1 = (size_t)colv[p + 1] * 32;
        const uint4 q0 = *(const uint4*)(z1 + j0);
        const uint4 q1 = *(const uint4*)(z1 + j0 + 8);
        const uint4 q2 = *(const uint4*)(z1 + j0 + 16);
        const uint4 q3 = *(const uint4*)(z1 + j0 + 24);
        const uint4 r0 = *(const uint4*)(z1 + j1);
        const uint4 r1 = *(const uint4*)(z1 + j1 + 8);
        const uint4 r2 = *(const uint4*)(z1 + j1 + 16);
        const uint4 r3 = *(const uint4*)(z1 + j1 + 24);
        H2x4 h;
        h.u = q0;
#pragma unroll
        for (int t = 0; t < 4; ++t) { const float2 f = __half22float2(h.h[t]); a[2*t] += f.x; a[2*t+1] += f.y; }
        h.u = q1;
#pragma unroll
        for (int t = 0; t < 4; ++t) { const float2 f = __half22float2(h.h[t]); a[8+2*t] += f.x; a[9+2*t] += f.y; }
        h.u = q2;
#pragma unroll
        for (int t = 0; t < 4; ++t) { const float2 f = __half22float2(h.h[t]); a[16+2*t] += f.x; a[17+2*t] += f.y; }
        h.u = q3;
#pragma unroll
        for (int t = 0; t < 4; ++t) { const float2 f = __half22float2(h.h[t]); a[24+2*t] += f.x; a[25+2*t] += f.y; }
        h.u = r0;
#pragma unroll
        for (int t = 0; t < 4; ++t) { const float2 f = __half22float2(h.h[t]); a[2*t] += f.x; a[2*t+1] += f.y; }
        h.u = r1;
#pragma unroll
        for (int t = 0; t < 4; ++t) { const float2 f = __half22float2(h.h[t]); a[8+2*t] += f.x; a[9+2*t] += f.y; }
        h.u = r2;
#pragma unroll
        for (int t = 0; t < 4; ++t) { const float2 f = __half22float2(h.h[t]); a[16+2*t] += f.x; a[17+2*t] += f.y; }
        h.u = r3;
#pragma unroll
        for (int t = 0; t < 4; ++t) { const float2 f = __half22float2(h.h[t]); a[24+2*t] += f.x; a[25+2*t] += f.y; }
    }
    if (p < e) {
        const size_t j0 = (size_t)colv[p] * 32;
        const uint4 q0 = *(const uint4*)(z1 + j0);
        const uint4 q1 = *(const uint4*)(z1 + j0 + 8);
        const uint4 q2 = *(const uint4*)(z1 + j0 + 16);
        const uint4 q3 = *(const uint4*)(z1 + j0 + 24);
        H2x4 h;
        h.u = q0;
#pragma unroll
        for (int t = 0; t < 4; ++t) { const float2 f = __half22float2(h.h[t]); a[2*t] += f.x; a[2*t+1] += f.y; }
        h.u = q1;
#pragma unroll
        for (int t = 0; t < 4; ++t) { const float2 f = __half22float2(h.h[t]); a[8+2*t] += f.x; a[9+2*t] += f.y; }
        h.u = q2;
#pragma unroll
        for (int t = 0; t < 4; ++t) { const float2 f = __half22float2(h.h[t]); a[16+2*t] += f.x; a[17+2*t] += f.y; }
        h.u = q3;
#pragma unroll
        for (int t = 0; t < 4; ++t) { const float2 f = __half22float2(h.h[t]); a[24+2*t] += f.x; a[25+2*t] += f.y; }
    }
    const float d = dis[i];
#pragma unroll
    for (int k = 0; k < 32; ++k) a[k] = fmaxf(d * a[k] + bh1[k], 0.f) * d;
    float o[8];
#pragma unroll
    for (int c = 0; c < 8; ++c) o[c] = 0.f;
#pragma unroll
    for (int k = 0; k < 32; ++k)
#pragma unroll
        for (int c = 0; c < 8; ++c) o[c] += a[k] * Wh2[k * 8 + c];
    H2x4 pk;
#pragma unroll
    for (int t = 0; t < 4; ++t) pk.h[t] = __float22half2_rn(make_float2(o[2 * t], o[2 * t + 1]));
    *(uint4*)(z2 + (size_t)i * 8) = pk.u;
}

// head: per-node gather of z2 (16B rows), relu-epilogue, x Wh3 -> z3 (prescaled)
__global__ __launch_bounds__(256) void h8to2_kernel(
    const __half* __restrict__ z2, const int* __restrict__ rptr,
    const int* __restrict__ colv, const float* __restrict__ dis,
    const float* __restrict__ bh2, const float* __restrict__ Wh3,
    __half* __restrict__ z3) {
    int i = blockIdx.x * blockDim.x + threadIdx.x;
    if (i >= NN) return;
    const int s = rptr[i], e = rptr[i + 1];
    float a[8];
#pragma unroll
    for (int k = 0; k < 8; ++k) a[k] = 0.f;
    int p = s;
    for (; p + 4 <= e; p += 4) {
        const uint4 q0 = *(const uint4*)(z2 + (size_t)colv[p] * 8);
        const uint4 q1 = *(const uint4*)(z2 + (size_t)colv[p + 1] * 8);
        const uint4 q2 = *(const uint4*)(z2 + (size_t)colv[p + 2] * 8);
        const uint4 q3 = *(const uint4*)(z2 + (size_t)colv[p + 3] * 8);
        H2x4 h;
        h.u = q0;
#pragma unroll
        for (int t = 0; t < 4; ++t) { const float2 f = __half22float2(h.h[t]); a[2*t] += f.x; a[2*t+1] += f.y; }
        h.u = q1;
#pragma unroll
        for (int t = 0; t < 4; ++t) { const float2 f = __half22float2(h.h[t]); a[2*t] += f.x; a[2*t+1] += f.y; }
        h.u = q2;
#pragma unroll
        for (int t = 0; t < 4; ++t) { const float2 f = __half22float2(h.h[t]); a[2*t] += f.x; a[2*t+1] += f.y; }
        h.u = q3;
#pragma unroll
        for (int t = 0; t < 4; ++t) { const float2 f = __half22float2(h.h[t]); a[2*t] += f.x; a[2*t+1] += f.y; }
    }
    for (; p < e; ++p) {
        const uint4 q0 = *(const uint4*)(z2 + (size_t)colv[p] * 8);
        H2x4 h;
        h.u = q0;
#pragma unroll
        for (int t = 0; t < 4; ++t) { const float2 f = __half22float2(h.h[t]); a[2*t] += f.x; a[2*t+1] += f.y; }
    }
    const float d = dis[i];
    float o0 = 0.f, o1 = 0.f;
#pragma unroll
    for (int k = 0; k < 8; ++k) {
        const float ak = fmaxf(d * a[k] + bh2[k], 0.f) * d;
        o0 += ak * Wh3[k * 2 + 0];
        o1 += ak * Wh3[k * 2 + 1];
    }
    ((__half2*)z3)[i] = __float22half2_rn(make_float2(o0, o1));
}

// head final: out = dis_i * sum_j z3[j] + bh3   (4B rows, L2-resident)
__global__ void final2_kernel(const __half* __restrict__ z3, const int* __restrict__ rptr,
                              const int* __restrict__ col, const float* __restrict__ dis,
                              const float* __restrict__ bh3, float* __restrict__ out) {
    int i = blockIdx.x * blockDim.x + threadIdx.x;
    if (i >= NN) return;
    const int s = rptr[i], e = rptr[i + 1];
    float a0 = 0.f, a1 = 0.f;
    int p = s;
    for (; p + 2 <= e; p += 2) {
        const __half2 h0 = ((const __half2*)z3)[col[p]];
        const __half2 h1 = ((const __half2*)z3)[col[p + 1]];
        const float2 f0 = __half22float2(h0);
        const float2 f1 = __half22float2(h1);
        a0 += f0.x + f1.x; a1 += f0.y + f1.y;
    }
    if (p < e) {
        const float2 f = __half22float2(((const __half2*)z3)[col[p]]);
        a0 += f.x; a1 += f.y;
    }
    const float d = dis[i];
    out[2 * i]     = d * a0 + bh3[0];
    out[2 * i + 1] = d * a1 + bh3[1];
}

// ---------------- fused GCN (64-wide main layers) ----------------
// h16 rows fp16, pre-scaled by dis[j]. agg_i = dis_i * sum_{j in row} h16[j].
// Phase 1: two rows jointly, straight-line, named vars only (R7 lesson).
// 3 masked gathers/row (capacity 24 >= deg mean 17; tail ~3% wave-uniform).
// ALL-fp16 tree reduce (3 rounds hadd2), fp32 convert only at slot==0.
// Phase 2: [64 x 64] fp32 @ W; addsrc fp16; WRAW -> unscaled fp16 (residual),
// W16 -> dis-prescaled fp16 (gather input). __launch_bounds__(256,6).

template <int IN_W, int OUT_W, bool RELU, bool HAS_ADD, bool HAS_BIAS, bool WRAW, bool W16>
__global__ __launch_bounds__(256, 6) void gcn_kernel(
    const __half* __restrict__ h16, const float* __restrict__ Wg,
    const float* __restrict__ bias, const __half* __restrict__ addsrc,
    const int* __restrict__ row_ptr, const int* __restrict__ colv,
    const float* __restrict__ dis,
    __half* __restrict__ outraw, __half* __restrict__ out16) {
    constexpr int TILE_R = 64;
    constexpr int QUADS = IN_W / 8;      // lanes per row (16B = 8 halves each)
    constexpr int SLOTS = 64 / QUADS;    // rows gathered per wave instruction
    constexpr int STR = IN_W + 4;
    __shared__ __align__(16) float aggT[TILE_R][STR];
    __shared__ int rp[TILE_R + 1];
    __shared__ float rdis[TILE_R];

    const int tid = threadIdx.x;
    const int tile0 = blockIdx.x * TILE_R;

    if (tid <= TILE_R) rp[tid] = row_ptr[min(tile0 + tid, NN)];
    if (tid < TILE_R) {
        const int i = tile0 + tid;
        rdis[tid] = (i < NN) ? dis[i] : 0.f;
    }
    __syncthreads();

    const int wave = tid >> 6;
    const int lane = tid & 63;
    const int fq = lane & (QUADS - 1);
    const int slot = lane / QUADS;
    const int rbase = wave << 4;
    const size_t fqo = (size_t)(fq << 3);

    const __half2 ONE2 = __float2half2_rn(1.0f);
    const __half2 ZERO2 = __float2half2_rn(0.0f);

    for (int hr = 0; hr < 8; ++hr) {
        const int rA = rbase + 2 * hr;
        const int rB = rA + 1;
        const int sA = __builtin_amdgcn_readfirstlane(rp[rA]);
        const int eA = __builtin_amdgcn_readfirstlane(rp[rA + 1]);
        const int sB = eA;
        const int eB = __builtin_amdgcn_readfirstlane(rp[rB + 1]);
        const int lastA = eA - 1, lastB = eB - 1;
        const int pA = sA + slot, pB = sB + slot;

        // 6 colv loads + 6 independent gathers (capacity 3*SLOTS=24 per row)
        const int jA0 = colv[min(pA, lastA)];
        const int jA1 = colv[min(pA + SLOTS, lastA)];
        const int jA2 = colv[min(pA + 2 * SLOTS, lastA)];
        const int jB0 = colv[min(pB, lastB)];
        const int jB1 = colv[min(pB + SLOTS, lastB)];
        const int jB2 = colv[min(pB + 2 * SLOTS, lastB)];
        const uint4 gA0 = *(const uint4*)(h16 + (size_t)jA0 * IN_W + fqo);
        const uint4 gA1 = *(const uint4*)(h16 + (size_t)jA1 * IN_W + fqo);
        const uint4 gA2 = *(const uint4*)(h16 + (size_t)jA2 * IN_W + fqo);
        const uint4 gB0 = *(const uint4*)(h16 + (size_t)jB0 * IN_W + fqo);
        const uint4 gB1 = *(const uint4*)(h16 + (size_t)jB1 * IN_W + fqo);
        const uint4 gB2 = *(const uint4*)(h16 + (size_t)jB2 * IN_W + fqo);

        __half2 aA[4] = {ZERO2, ZERO2, ZERO2, ZERO2};
        __half2 aB[4] = {ZERO2, ZERO2, ZERO2, ZERO2};
        {
            H2x4 hh;
            const __half2 mA0 = (pA < eA) ? ONE2 : ZERO2;
            const __half2 mA1 = (pA + SLOTS < eA) ? ONE2 : ZERO2;
            const __half2 mA2 = (pA + 2 * SLOTS < eA) ? ONE2 : ZERO2;
            const __half2 mB0 = (pB < eB) ? ONE2 : ZERO2;
            const __half2 mB1 = (pB + SLOTS < eB) ? ONE2 : ZERO2;
            const __half2 mB2 = (pB + 2 * SLOTS < eB) ? ONE2 : ZERO2;
            hh.u = gA0;
#pragma unroll
            for (int t = 0; t < 4; ++t) aA[t] = __hfma2(hh.h[t], mA0, aA[t]);
            hh.u = gA1;
#pragma unroll
            for (int t = 0; t < 4; ++t) aA[t] = __hfma2(hh.h[t], mA1, aA[t]);
            hh.u = gA2;
#pragma unroll
            for (int t = 0; t < 4; ++t) aA[t] = __hfma2(hh.h[t], mA2, aA[t]);
            hh.u = gB0;
#pragma unroll
            for (int t = 0; t < 4; ++t) aB[t] = __hfma2(hh.h[t], mB0, aB[t]);
            hh.u = gB1;
#pragma unroll
            for (int t = 0; t < 4; ++t) aB[t] = __hfma2(hh.h[t], mB1, aB[t]);
            hh.u = gB2;
#pragma unroll
            for (int t = 0; t < 4; ++t) aB[t] = __hfma2(hh.h[t], mB2, aB[t]);
        }
        // rare tails (deg > 3*SLOTS, ~3%): wave-uniform branches
        if (eA - sA > 3 * SLOTS) {
            H2x4 hh;
            for (int p = pA + 3 * SLOTS; p < eA; p += SLOTS) {
                hh.u = *(const uint4*)(h16 + (size_t)colv[p] * IN_W + fqo);
#pragma unroll
                for (int t = 0; t < 4; ++t) aA[t] = __hadd2(aA[t], hh.h[t]);
            }
        }
        if (eB - sB > 3 * SLOTS) {
            H2x4 hh;
            for (int p = pB + 3 * SLOTS; p < eB; p += SLOTS) {
                hh.u = *(const uint4*)(h16 + (size_t)colv[p] * IN_W + fqo);
#pragma unroll
                for (int t = 0; t < 4; ++t) aB[t] = __hadd2(aB[t], hh.h[t]);
            }
        }
        // all-fp16 tree reduce across slots (3 rounds for SLOTS=8)
#pragma unroll
        for (int m = QUADS; m < 64; m <<= 1) {
#pragma unroll
            for (int t = 0; t < 4; ++t) {
                int vA = __shfl_xor(*reinterpret_cast<const int*>(&aA[t]), m, 64);
                int vB = __shfl_xor(*reinterpret_cast<const int*>(&aB[t]), m, 64);
                aA[t] = __hadd2(aA[t], *reinterpret_cast<const __half2*>(&vA));
                aB[t] = __hadd2(aB[t], *reinterpret_cast<const __half2*>(&vB));
            }
        }
        if (slot == 0) {
            const float dA = rdis[rA], dB = rdis[rB];
            float fA[8], fB[8];
#pragma unroll
            for (int t = 0; t < 4; ++t) {
                const float2 qA = __half22float2(aA[t]);
                const float2 qB = __half22float2(aB[t]);
                fA[2 * t] = qA.x * dA; fA[2 * t + 1] = qA.y * dA;
                fB[2 * t] = qB.x * dB; fB[2 * t + 1] = qB.y * dB;
            }
            *(float4*)&aggT[rA][(fq << 3)]     = make_float4(fA[0], fA[1], fA[2], fA[3]);
            *(float4*)&aggT[rA][(fq << 3) + 4] = make_float4(fA[4], fA[5], fA[6], fA[7]);
            *(float4*)&aggT[rB][(fq << 3)]     = make_float4(fB[0], fB[1], fB[2], fB[3]);
            *(float4*)&aggT[rB][(fq << 3) + 4] = make_float4(fB[4], fB[5], fB[6], fB[7]);
        }
    }
    __syncthreads();

    // phase 2: [64 x IN_W] fp32 @ [IN_W x OUT_W], W from global (L1-resident)
    constexpr int CPT = 4;
    constexpr int TXN = OUT_W / CPT;
    const int tx = tid % TXN;
    const int ty = tid / TXN;
    if (ty < TILE_R / 4) {
        float c[4][CPT];
#pragma unroll
        for (int r = 0; r < 4; ++r)
#pragma unroll
            for (int q = 0; q < CPT; ++q) c[r][q] = 0.f;

#pragma unroll 2
        for (int k4 = 0; k4 < IN_W / 4; ++k4) {
            float4 av[4];
#pragma unroll
            for (int r = 0; r < 4; ++r) av[r] = *(const float4*)&aggT[ty * 4 + r][k4 << 2];
#pragma unroll
            for (int kk = 0; kk < 4; ++kk) {
                const float4 w4 = *(const float4*)(Wg + ((k4 << 2) + kk) * OUT_W + (tx << 2));
                float wv[CPT] = {w4.x, w4.y, w4.z, w4.w};
#pragma unroll
                for (int r = 0; r < 4; ++r) {
                    const float ar = ((const float*)&av[r])[kk];
#pragma unroll
                    for (int q = 0; q < CPT; ++q) c[r][q] += ar * wv[q];
                }
            }
        }
        float bq[CPT];
#pragma unroll
        for (int q = 0; q < CPT; ++q) bq[q] = HAS_BIAS ? bias[tx * CPT + q] : 0.f;
#pragma unroll
        for (int r = 0; r < 4; ++r) {
            const int i = tile0 + ty * 4 + r;
            if (i < NN) {
                float o[CPT];
#pragma unroll
                for (int q = 0; q < CPT; ++q) o[q] = c[r][q] + bq[q];
                if constexpr (HAS_ADD) {
                    H2x2 ad;
                    ad.u = *(const uint2*)(addsrc + (size_t)i * OUT_W + (tx << 2));
#pragma unroll
                    for (int t = 0; t < 2; ++t) {
                        const float2 f = __half22float2(ad.h[t]);
                        o[2 * t] += f.x; o[2 * t + 1] += f.y;
                    }
                }
                if constexpr (RELU) {
#pragma unroll
                    for (int q = 0; q < CPT; ++q) o[q] = fmaxf(o[q], 0.f);
                }
                if constexpr (WRAW) {
                    H2x2 pk;
                    pk.h[0] = __float22half2_rn(make_float2(o[0], o[1]));
                    pk.h[1] = __float22half2_rn(make_float2(o[2], o[3]));
                    *(uint2*)(outraw + (size_t)i * OUT_W + (tx << 2)) = pk.u;
                }
                if constexpr (W16) {
                    const float d = dis[i];
                    H2x2 pk;
                    pk.h[0] = __float22half2_rn(make_float2(o[0] * d, o[1] * d));
                    pk.h[1] = __float22half2_rn(make_float2(o[2] * d, o[3] * d));
                    *(uint2*)(out16 + (size_t)i * OUT_W + (tx << 2)) = pk.u;
                }
            }
        }
    }
}

// ---------------- driver ----------------

extern "C" void kernel_launch(void* const* d_in, const int* in_sizes, int n_in,
                              void* d_out, int out_size, void* d_ws, size_t ws_size,
                              hipStream_t stream) {
    const float* x   = (const float*)d_in[0];
    const float* Wp  = (const float*)d_in[1];
    const float* bp  = (const float*)d_in[2];
    const float* Wr  = (const float*)d_in[3];
    const float* br  = (const float*)d_in[4];
    const float* W11 = (const float*)d_in[5];
    const float* b11 = (const float*)d_in[6];
    const float* W12 = (const float*)d_in[7];
    const float* b12 = (const float*)d_in[8];
    const float* W21 = (const float*)d_in[9];
    const float* b21 = (const float*)d_in[10];
    const float* W22 = (const float*)d_in[11];
    const float* b22 = (const float*)d_in[12];
    const float* Wh1 = (const float*)d_in[13];
    const float* bh1 = (const float*)d_in[14];
    const float* Wh2 = (const float*)d_in[15];
    const float* bh2 = (const float*)d_in[16];
    const float* Wh3 = (const float*)d_in[17];
    const float* bh3 = (const float*)d_in[18];
    const int* edge  = (const int*)d_in[19];
    const int* srcA = edge;
    const int* dstA = edge + NE;
    float* outp = (float*)d_out;

    char* p = (char*)d_ws;
    auto carve = [&](size_t bytes) {
        char* r = p;
        p += (bytes + 255) & ~(size_t)255;
        return r;
    };
    int*      cnt   = (int*)carve(NN * 4);
    int*      rptr  = (int*)carve((NN + 1) * 4);
    float*    dis   = (float*)carve(NN * 4);
    int*      sums  = (int*)carve(128 * 4);
    int*      gcnt  = (int*)carve(256 * 4);
    unsigned* bins  = (unsigned*)carve((size_t)NBUCK * BCAP * 4);
    int*      colv  = (int*)carve((size_t)(NE + NN + 256) * 4);
    float4*   xs4   = (float4*)carve((size_t)NN * 16);
    float*    ax    = (float*)carve((size_t)NN * 3 * 4);
    __half*   xr16  = (__half*)carve((size_t)NN * 64 * 2);
    __half*   bu16b = (__half*)carve((size_t)NN * 64 * 2);
    __half*   bw16b = (__half*)carve((size_t)NN * 64 * 2);
    __half*   bt16  = (__half*)carve((size_t)NN * 64 * 2);
    __half*   bu16  = (__half*)carve((size_t)NN * 64 * 2);
    __half*   bv16  = (__half*)carve((size_t)NN * 64 * 2);
    __half*   bw16  = (__half*)carve((size_t)NN * 64 * 2);
    // head reuse (dead after main loop)
    __half*   z1    = bv16;   // NN x 32
    __half*   z2    = bw16;   // NN x 8
    __half*   z3    = bu16;   // NN x 2

    hipMemsetAsync(gcnt, 0, 256 * 4, stream);
    const int GA = (NE + PA_EDGES - 1) / PA_EDGES;
    binA_kernel<<<GA, 256, 0, stream>>>(srcA, dstA, gcnt, bins);
    binB1_kernel<<<NBUCK, 256, 0, stream>>>(bins, gcnt, cnt);
    dis_xs_kernel<<<(NN + 255) / 256, 256, 0, stream>>>(cnt, x, dis, xs4);
    scan1_kernel<<<NCHUNK, 256, 0, stream>>>(cnt, rptr, sums);
    scan2_kernel<<<1, 128, 0, stream>>>(sums, rptr);
    scan3_kernel<<<(NN + 255) / 256, 256, 0, stream>>>(rptr, sums);
    binB2_kernel<<<NBUCK, 256, 0, stream>>>(bins, gcnt, rptr, colv);
    selffill_kernel<<<(NN + 255) / 256, 256, 0, stream>>>(rptr, cnt, colv);
    aggx_kernel<<<(NN + 255) / 256, 256, 0, stream>>>(xs4, rptr, colv, dis, ax);
    proj_kernel<<<(NN * 64 + 255) / 256, 256, 0, stream>>>(ax, Wp, bp, Wr, br, dis, bt16, xr16);

    const int GB = (NN + 63) / 64;
    for (int it = 0; it < 5; ++it) {
        gcn_kernel<64, 64, false, true, false, true, true><<<GB, 256, 0, stream>>>(
            bt16, Wr, nullptr, xr16, rptr, colv, dis, bu16b, bu16);
        gcn_kernel<64, 64, true, false, true, false, true><<<GB, 256, 0, stream>>>(
            bu16, W11, b11, nullptr, rptr, colv, dis, nullptr, bv16);
        gcn_kernel<64, 64, true, true, true, true, true><<<GB, 256, 0, stream>>>(
            bv16, W12, b12, bu16b, rptr, colv, dis, bw16b, bw16);
        gcn_kernel<64, 64, true, false, true, false, true><<<GB, 256, 0, stream>>>(
            bw16, W21, b21, nullptr, rptr, colv, dis, nullptr, bv16);
        gcn_kernel<64, 64, true, true, true, false, true><<<GB, 256, 0, stream>>>(
            bv16, W22, b22, bw16b, rptr, colv, dis, nullptr, bt16);
    }
    // head, multiply-first, per-node narrow kernels
    mmh1_kernel<<<(NN * 32 + 255) / 256, 256, 0, stream>>>(bt16, Wh1, z1);
    h32to8_kernel<<<(NN + 255) / 256, 256, 0, stream>>>(z1, rptr, colv, dis, bh1, Wh2, z2);
    h8to2_kernel<<<(NN + 255) / 256, 256, 0, stream>>>(z2, rptr, colv, dis, bh2, Wh3, z3);
    final2_kernel<<<(NN + 255) / 256, 256, 0, stream>>>(z3, rptr, colv, dis, bh3, outp);
}

// Round 13
// 1188.237 us; speedup vs baseline: 1.3383x; 1.2822x over previous
//
#include <hip/hip_runtime.h>
#include <hip/hip_fp16.h>

#define NN 100000
#define NE 1600000
#define CHUNK 1024
#define NCHUNK ((NN + CHUNK - 1) / CHUNK)
#define NBUCK 196            // dst >> 9  (512 nodes per bucket)
#define BCAP 9216            // mean 8192, sigma ~90 -> +11 sigma
#define PA_EDGES 4096

union H2x4 { uint4 u; __half2 h[4]; };
union H2x2 { uint2 u; __half2 h[2]; };

typedef __attribute__((ext_vector_type(8))) _Float16 half8;
typedef __attribute__((ext_vector_type(4))) float f32x4;

// ---------------- CSR build: two-pass LDS radix binning ----------------

__global__ __launch_bounds__(256) void binA_kernel(const int* __restrict__ src,
                                                   const int* __restrict__ dst,
                                                   int* __restrict__ gcnt,
                                                   unsigned* __restrict__ bins) {
    __shared__ int lcnt[256], lofs[256], lfil[256], gbase[256];
    __shared__ unsigned stage[PA_EDGES];
    const int tid = threadIdx.x;
    const int e0 = blockIdx.x * PA_EDGES;
    lcnt[tid] = 0; lfil[tid] = 0;
    __syncthreads();
    for (int k = 0; k < PA_EDGES / 256; ++k) {
        const int e = e0 + k * 256 + tid;
        if (e < NE) atomicAdd(&lcnt[dst[e] >> 9], 1);
    }
    __syncthreads();
    const int v = lcnt[tid];
    lofs[tid] = v;
    __syncthreads();
    for (int off = 1; off < 256; off <<= 1) {
        int xv = (tid >= off) ? lofs[tid - off] : 0;
        __syncthreads();
        lofs[tid] += xv;
        __syncthreads();
    }
    const int excl = lofs[tid] - v;
    __syncthreads();
    lofs[tid] = excl;
    if (tid < NBUCK && v > 0) gbase[tid] = atomicAdd(&gcnt[tid], v);
    else gbase[tid] = 0;
    __syncthreads();
    for (int k = 0; k < PA_EDGES / 256; ++k) {
        const int e = e0 + k * 256 + tid;
        if (e < NE) {
            const int d = dst[e];
            const int b = d >> 9;
            const int p = atomicAdd(&lfil[b], 1);
            stage[lofs[b] + p] = ((unsigned)src[e] << 9) | (unsigned)(d & 511);
        }
    }
    __syncthreads();
    const int wave = tid >> 6, lane = tid & 63;
    for (int b = wave; b < NBUCK; b += 4) {
        const int n = lcnt[b];
        const int base = gbase[b];
        const int off = lofs[b];
        for (int k = lane; k < n; k += 64) {
            const int gpos = base + k;
            if (gpos < BCAP) bins[(size_t)b * BCAP + gpos] = stage[off + k];
        }
    }
}

__global__ __launch_bounds__(256) void binB1_kernel(const unsigned* __restrict__ bins,
                                                    const int* __restrict__ gcnt,
                                                    int* __restrict__ cnt) {
    __shared__ int c512[512];
    const int b = blockIdx.x, tid = threadIdx.x;
    c512[tid] = 0; c512[256 + tid] = 0;
    __syncthreads();
    const int n = min(gcnt[b], BCAP);
    for (int k = tid; k < n; k += 256)
        atomicAdd(&c512[bins[(size_t)b * BCAP + k] & 511], 1);
    __syncthreads();
    const int i0 = b * 512 + tid;
    const int i1 = i0 + 256;
    if (i0 < NN) cnt[i0] = c512[tid];
    if (i1 < NN) cnt[i1] = c512[256 + tid];
}

__global__ __launch_bounds__(256) void binB2_kernel(const unsigned* __restrict__ bins,
                                                    const int* __restrict__ gcnt,
                                                    const int* __restrict__ rptr,
                                                    int* __restrict__ col) {
    __shared__ int fil512[512];
    __shared__ int rp_l[512];
    const int b = blockIdx.x, tid = threadIdx.x;
    fil512[tid] = 0; fil512[256 + tid] = 0;
    const int i0 = b * 512 + tid;
    const int i1 = i0 + 256;
    rp_l[tid]       = (i0 < NN) ? rptr[i0] : 0;
    rp_l[256 + tid] = (i1 < NN) ? rptr[i1] : 0;
    __syncthreads();
    const int n = min(gcnt[b], BCAP);
    for (int k = tid; k < n; k += 256) {
        const unsigned w = bins[(size_t)b * BCAP + k];
        const int dl = (int)(w & 511);
        const int s = (int)(w >> 9);
        const int p = atomicAdd(&fil512[dl], 1);
        col[rp_l[dl] + p] = s;
    }
}

// dis[i] = rsqrt(deg_i+1);  xs4 = dis-prescaled x rows, padded to float4
__global__ void dis_xs_kernel(const int* __restrict__ cnt, const float* __restrict__ x,
                              float* __restrict__ dis, float4* __restrict__ xs4) {
    int i = blockIdx.x * blockDim.x + threadIdx.x;
    if (i >= NN) return;
    float d = rsqrtf((float)(cnt[i] + 1));
    dis[i] = d;
    xs4[i] = make_float4(d * x[i * 3 + 0], d * x[i * 3 + 1], d * x[i * 3 + 2], 0.f);
}

// hierarchical exclusive scan of (cnt[i]+1)  [self-loop included in CSR]
__global__ __launch_bounds__(256) void scan1_kernel(const int* __restrict__ cnt,
                                                    int* __restrict__ row_ptr,
                                                    int* __restrict__ sums) {
    __shared__ int sdata[256];
    const int b = blockIdx.x, t = threadIdx.x;
    const int base = b * CHUNK + t * 4;
    int v0 = (base + 0 < NN) ? cnt[base + 0] + 1 : 0;
    int v1 = (base + 1 < NN) ? cnt[base + 1] + 1 : 0;
    int v2 = (base + 2 < NN) ? cnt[base + 2] + 1 : 0;
    int v3 = (base + 3 < NN) ? cnt[base + 3] + 1 : 0;
    const int s = v0 + v1 + v2 + v3;
    sdata[t] = s;
    __syncthreads();
    for (int off = 1; off < 256; off <<= 1) {
        int xv = (t >= off) ? sdata[t - off] : 0;
        __syncthreads();
        sdata[t] += xv;
        __syncthreads();
    }
    const int excl = sdata[t] - s;
    if (base + 0 < NN) row_ptr[base + 0] = excl;
    if (base + 1 < NN) row_ptr[base + 1] = excl + v0;
    if (base + 2 < NN) row_ptr[base + 2] = excl + v0 + v1;
    if (base + 3 < NN) row_ptr[base + 3] = excl + v0 + v1 + v2;
    if (t == 255) sums[b] = sdata[255];
}

__global__ __launch_bounds__(128) void scan2_kernel(int* __restrict__ sums,
                                                    int* __restrict__ row_ptr) {
    __shared__ int sd[128];
    const int t = threadIdx.x;
    const int v = (t < NCHUNK) ? sums[t] : 0;
    sd[t] = v;
    __syncthreads();
    for (int off = 1; off < 128; off <<= 1) {
        int xv = (t >= off) ? sd[t - off] : 0;
        __syncthreads();
        sd[t] += xv;
        __syncthreads();
    }
    if (t < NCHUNK) sums[t] = sd[t] - v;
    if (t == 127) row_ptr[NN] = sd[127];
}

__global__ void scan3_kernel(int* __restrict__ row_ptr, const int* __restrict__ sums) {
    int i = blockIdx.x * blockDim.x + threadIdx.x;
    if (i < NN) row_ptr[i] += sums[i >> 10];
}

__global__ void selffill_kernel(const int* __restrict__ row_ptr, const int* __restrict__ cnt,
                                int* __restrict__ col) {
    int i = blockIdx.x * blockDim.x + threadIdx.x;
    if (i >= NN) return;
    col[row_ptr[i] + cnt[i]] = i;  // self edge last in the row
}

// ax = Ahat @ x = dis_i * sum_j xs[j]   (CSR includes self loop)
__global__ void aggx_kernel(const float4* __restrict__ xs4, const int* __restrict__ row_ptr,
                            const int* __restrict__ col, const float* __restrict__ dis,
                            float* __restrict__ ax) {
    int i = blockIdx.x * blockDim.x + threadIdx.x;
    if (i >= NN) return;
    float a0 = 0.f, a1 = 0.f, a2 = 0.f;
    const int s = row_ptr[i], e = row_ptr[i + 1];
    int p = s;
    for (; p + 2 <= e; p += 2) {
        const float4 v0 = xs4[col[p]];
        const float4 v1 = xs4[col[p + 1]];
        a0 += v0.x + v1.x; a1 += v0.y + v1.y; a2 += v0.z + v1.z;
    }
    if (p < e) {
        const float4 v = xs4[col[p]];
        a0 += v.x; a1 += v.y; a2 += v.z;
    }
    const float d = dis[i];
    ax[i * 3 + 0] = d * a0; ax[i * 3 + 1] = d * a1; ax[i * 3 + 2] = d * a2;
}

// t16 = fp16(dis * relu(ax @ Wp + bp));  xr16 = fp16(ax @ Wr[64:67,:] + br)
__global__ void proj_kernel(const float* __restrict__ ax,
                            const float* __restrict__ Wp, const float* __restrict__ bp,
                            const float* __restrict__ Wr, const float* __restrict__ br,
                            const float* __restrict__ dis,
                            __half* __restrict__ t16, __half* __restrict__ xr16) {
    int g = blockIdx.x * blockDim.x + threadIdx.x;
    if (g >= NN * 64) return;
    int i = g >> 6, c = g & 63;
    float a0 = ax[i * 3 + 0], a1 = ax[i * 3 + 1], a2 = ax[i * 3 + 2];
    float tp = fmaxf(a0 * Wp[c] + a1 * Wp[64 + c] + a2 * Wp[128 + c] + bp[c], 0.f);
    t16[g] = __float2half(tp * dis[i]);
    xr16[g] = __float2half(a0 * Wr[64 * 64 + c] + a1 * Wr[65 * 64 + c] + a2 * Wr[66 * 64 + c] + br[c]);
}

// head dense: z1 = bt16 @ Wh1  (rows already dis-prescaled; multiply-first)
__global__ void mmh1_kernel(const __half* __restrict__ bt, const float* __restrict__ Wh1,
                            __half* __restrict__ z1) {
    int g = blockIdx.x * blockDim.x + threadIdx.x;
    if (g >= NN * 32) return;
    const int i = g >> 5, c = g & 31;
    const __half* row = bt + (size_t)i * 64;
    float acc = 0.f;
#pragma unroll
    for (int k4 = 0; k4 < 8; ++k4) {
        H2x4 r;
        r.u = ((const uint4*)row)[k4];
#pragma unroll
        for (int t = 0; t < 4; ++t) {
            const float2 f = __half22float2(r.h[t]);
            acc += f.x * Wh1[(k4 * 8 + 2 * t) * 32 + c];
            acc += f.y * Wh1[(k4 * 8 + 2 * t + 1) * 32 + c];
        }
    }
    z1[g] = __float2half(acc);
}

// head: per-node gather of z1 (64B rows), relu-epilogue, x Wh2 -> z2 (prescaled)
__global__ __launch_bounds__(256) void h32to8_kernel(
    const __half* __restrict__ z1, const int* __restrict__ rptr,
    const int* __restrict__ colv, const float* __restrict__ dis,
    const float* __restrict__ bh1, const float* __restrict__ Wh2,
    __half* __restrict__ z2) {
    int i = blockIdx.x * blockDim.x + threadIdx.x;
    if (i >= NN) return;
    const int s = rptr[i], e = rptr[i + 1];
    float a[32];
#pragma unroll
    for (int k = 0; k < 32; ++k) a[k] = 0.f;
    int p = s;
    for (; p + 2 <= e; p += 2) {
        const size_t j0 = (size_t)colv[p] * 32, j1 = (size_t)colv[p + 1] * 32;
        const uint4 q0 = *(const uint4*)(z1 + j0);
        const uint4 q1 = *(const uint4*)(z1 + j0 + 8);
        const uint4 q2 = *(const uint4*)(z1 + j0 + 16);
        const uint4 q3 = *(const uint4*)(z1 + j0 + 24);
        const uint4 r0 = *(const uint4*)(z1 + j1);
        const uint4 r1 = *(const uint4*)(z1 + j1 + 8);
        const uint4 r2 = *(const uint4*)(z1 + j1 + 16);
        const uint4 r3 = *(const uint4*)(z1 + j1 + 24);
        H2x4 h;
        h.u = q0;
#pragma unroll
        for (int t = 0; t < 4; ++t) { const float2 f = __half22float2(h.h[t]); a[2*t] += f.x; a[2*t+1] += f.y; }
        h.u = q1;
#pragma unroll
        for (int t = 0; t < 4; ++t) { const float2 f = __half22float2(h.h[t]); a[8+2*t] += f.x; a[9+2*t] += f.y; }
        h.u = q2;
#pragma unroll
        for (int t = 0; t < 4; ++t) { const float2 f = __half22float2(h.h[t]); a[16+2*t] += f.x; a[17+2*t] += f.y; }
        h.u = q3;
#pragma unroll
        for (int t = 0; t < 4; ++t) { const float2 f = __half22float2(h.h[t]); a[24+2*t] += f.x; a[25+2*t] += f.y; }
        h.u = r0;
#pragma unroll
        for (int t = 0; t < 4; ++t) { const float2 f = __half22float2(h.h[t]); a[2*t] += f.x; a[2*t+1] += f.y; }
        h.u = r1;
#pragma unroll
        for (int t = 0; t < 4; ++t) { const float2 f = __half22float2(h.h[t]); a[8+2*t] += f.x; a[9+2*t] += f.y; }
        h.u = r2;
#pragma unroll
        for (int t = 0; t < 4; ++t) { const float2 f = __half22float2(h.h[t]); a[16+2*t] += f.x; a[17+2*t] += f.y; }
        h.u = r3;
#pragma unroll
        for (int t = 0; t < 4; ++t) { const float2 f = __half22float2(h.h[t]); a[24+2*t] += f.x; a[25+2*t] += f.y; }
    }
    if (p < e) {
        const size_t j0 = (size_t)colv[p] * 32;
        const uint4 q0 = *(const uint4*)(z1 + j0);
        const uint4 q1 = *(const uint4*)(z1 + j0 + 8);
        const uint4 q2 = *(const uint4*)(z1 + j0 + 16);
        const uint4 q3 = *(const uint4*)(z1 + j0 + 24);
        H2x4 h;
        h.u = q0;
#pragma unroll
        for (int t = 0; t < 4; ++t) { const float2 f = __half22float2(h.h[t]); a[2*t] += f.x; a[2*t+1] += f.y; }
        h.u = q1;
#pragma unroll
        for (int t = 0; t < 4; ++t) { const float2 f = __half22float2(h.h[t]); a[8+2*t] += f.x; a[9+2*t] += f.y; }
        h.u = q2;
#pragma unroll
        for (int t = 0; t < 4; ++t) { const float2 f = __half22float2(h.h[t]); a[16+2*t] += f.x; a[17+2*t] += f.y; }
        h.u = q3;
#pragma unroll
        for (int t = 0; t < 4; ++t) { const float2 f = __half22float2(h.h[t]); a[24+2*t] += f.x; a[25+2*t] += f.y; }
    }
    const float d = dis[i];
#pragma unroll
    for (int k = 0; k < 32; ++k) a[k] = fmaxf(d * a[k] + bh1[k], 0.f) * d;
    float o[8];
#pragma unroll
    for (int c = 0; c < 8; ++c) o[c] = 0.f;
#pragma unroll
    for (int k = 0; k < 32; ++k)
#pragma unroll
        for (int c = 0; c < 8; ++c) o[c] += a[k] * Wh2[k * 8 + c];
    H2x4 pk;
#pragma unroll
    for (int t = 0; t < 4; ++t) pk.h[t] = __float22half2_rn(make_float2(o[2 * t], o[2 * t + 1]));
    *(uint4*)(z2 + (size_t)i * 8) = pk.u;
}

// head: per-node gather of z2 (16B rows), relu-epilogue, x Wh3 -> z3 (prescaled)
__global__ __launch_bounds__(256) void h8to2_kernel(
    const __half* __restrict__ z2, const int* __restrict__ rptr,
    const int* __restrict__ colv, const float* __restrict__ dis,
    const float* __restrict__ bh2, const float* __restrict__ Wh3,
    __half* __restrict__ z3) {
    int i = blockIdx.x * blockDim.x + threadIdx.x;
    if (i >= NN) return;
    const int s = rptr[i], e = rptr[i + 1];
    float a[8];
#pragma unroll
    for (int k = 0; k < 8; ++k) a[k] = 0.f;
    int p = s;
    for (; p + 4 <= e; p += 4) {
        const uint4 q0 = *(const uint4*)(z2 + (size_t)colv[p] * 8);
        const uint4 q1 = *(const uint4*)(z2 + (size_t)colv[p + 1] * 8);
        const uint4 q2 = *(const uint4*)(z2 + (size_t)colv[p + 2] * 8);
        const uint4 q3 = *(const uint4*)(z2 + (size_t)colv[p + 3] * 8);
        H2x4 h;
        h.u = q0;
#pragma unroll
        for (int t = 0; t < 4; ++t) { const float2 f = __half22float2(h.h[t]); a[2*t] += f.x; a[2*t+1] += f.y; }
        h.u = q1;
#pragma unroll
        for (int t = 0; t < 4; ++t) { const float2 f = __half22float2(h.h[t]); a[2*t] += f.x; a[2*t+1] += f.y; }
        h.u = q2;
#pragma unroll
        for (int t = 0; t < 4; ++t) { const float2 f = __half22float2(h.h[t]); a[2*t] += f.x; a[2*t+1] += f.y; }
        h.u = q3;
#pragma unroll
        for (int t = 0; t < 4; ++t) { const float2 f = __half22float2(h.h[t]); a[2*t] += f.x; a[2*t+1] += f.y; }
    }
    for (; p < e; ++p) {
        const uint4 q0 = *(const uint4*)(z2 + (size_t)colv[p] * 8);
        H2x4 h;
        h.u = q0;
#pragma unroll
        for (int t = 0; t < 4; ++t) { const float2 f = __half22float2(h.h[t]); a[2*t] += f.x; a[2*t+1] += f.y; }
    }
    const float d = dis[i];
    float o0 = 0.f, o1 = 0.f;
#pragma unroll
    for (int k = 0; k < 8; ++k) {
        const float ak = fmaxf(d * a[k] + bh2[k], 0.f) * d;
        o0 += ak * Wh3[k * 2 + 0];
        o1 += ak * Wh3[k * 2 + 1];
    }
    ((__half2*)z3)[i] = __float22half2_rn(make_float2(o0, o1));
}

// head final: out = dis_i * sum_j z3[j] + bh3   (4B rows, L2-resident)
__global__ void final2_kernel(const __half* __restrict__ z3, const int* __restrict__ rptr,
                              const int* __restrict__ col, const float* __restrict__ dis,
                              const float* __restrict__ bh3, float* __restrict__ out) {
    int i = blockIdx.x * blockDim.x + threadIdx.x;
    if (i >= NN) return;
    const int s = rptr[i], e = rptr[i + 1];
    float a0 = 0.f, a1 = 0.f;
    int p = s;
    for (; p + 2 <= e; p += 2) {
        const __half2 h0 = ((const __half2*)z3)[col[p]];
        const __half2 h1 = ((const __half2*)z3)[col[p + 1]];
        const float2 f0 = __half22float2(h0);
        const float2 f1 = __half22float2(h1);
        a0 += f0.x + f1.x; a1 += f0.y + f1.y;
    }
    if (p < e) {
        const float2 f = __half22float2(((const __half2*)z3)[col[p]]);
        a0 += f.x; a1 += f.y;
    }
    const float d = dis[i];
    out[2 * i]     = d * a0 + bh3[0];
    out[2 * i + 1] = d * a1 + bh3[1];
}

// ---------------- fused GCN (64x64 main layers) ----------------
// Phase 1 (unchanged from R12): two rows jointly, 3 masked gathers/row,
// all-fp16 tree reduce; dis-scaled agg now stored to LDS as FP16.
// Phase 2 (NEW): MFMA. Wave w computes output rows [16w,16w+16):
//   C(16x64) = A(16x64 fp16, LDS) @ W(64x64 fp16, LDS transposed),
//   via 8 x v_mfma_f32_16x16x32_f16 (2 K-chunks x 4 n-tiles).
// Fragment layouts: A[m=lane&15][k=quad*8+j]; B mirrored (n=lane&15);
// C/D col=lane&15, row=quad*4+reg (HW-verified layouts per guide).

template <bool RELU, bool HAS_ADD, bool HAS_BIAS, bool WRAW, bool W16>
__global__ __launch_bounds__(256, 6) void gcn_kernel(
    const __half* __restrict__ h16, const float* __restrict__ Wg,
    const float* __restrict__ bias, const __half* __restrict__ addsrc,
    const int* __restrict__ row_ptr, const int* __restrict__ colv,
    const float* __restrict__ dis,
    __half* __restrict__ outraw, __half* __restrict__ out16) {
    constexpr int TILE_R = 64;
    constexpr int IN_W = 64;
    constexpr int QUADS = 8;             // lanes per row (16B = 8 halves each)
    constexpr int SLOTS = 8;             // rows gathered per wave instruction
    constexpr int STR2 = IN_W + 8;       // halves; 16B-aligned rows
    __shared__ __align__(16) __half aggT16[TILE_R][STR2];
    __shared__ __align__(16) __half Wt16[IN_W][STR2];   // Wt16[n][k] = W[k][n]
    __shared__ int rp[TILE_R + 1];
    __shared__ float rdis[TILE_R];

    const int tid = threadIdx.x;
    const int tile0 = blockIdx.x * TILE_R;

    // stage W transposed into LDS as fp16 (B-operand layout wants n-major)
    for (int idx = tid; idx < 64 * 64; idx += 256) {
        const int k = idx >> 6, n = idx & 63;
        Wt16[n][k] = __float2half(Wg[idx]);
    }
    if (tid <= TILE_R) rp[tid] = row_ptr[min(tile0 + tid, NN)];
    if (tid < TILE_R) {
        const int i = tile0 + tid;
        rdis[tid] = (i < NN) ? dis[i] : 0.f;
    }
    __syncthreads();

    const int wave = tid >> 6;
    const int lane = tid & 63;
    const int fq = lane & (QUADS - 1);
    const int slot = lane / QUADS;
    const int rbase = wave << 4;
    const size_t fqo = (size_t)(fq << 3);

    const __half2 ONE2 = __float2half2_rn(1.0f);
    const __half2 ZERO2 = __float2half2_rn(0.0f);

    for (int hr = 0; hr < 8; ++hr) {
        const int rA = rbase + 2 * hr;
        const int rB = rA + 1;
        const int sA = __builtin_amdgcn_readfirstlane(rp[rA]);
        const int eA = __builtin_amdgcn_readfirstlane(rp[rA + 1]);
        const int sB = eA;
        const int eB = __builtin_amdgcn_readfirstlane(rp[rB + 1]);
        const int lastA = eA - 1, lastB = eB - 1;
        const int pA = sA + slot, pB = sB + slot;

        // 6 colv loads + 6 independent gathers (capacity 3*SLOTS=24 per row)
        const int jA0 = colv[min(pA, lastA)];
        const int jA1 = colv[min(pA + SLOTS, lastA)];
        const int jA2 = colv[min(pA + 2 * SLOTS, lastA)];
        const int jB0 = colv[min(pB, lastB)];
        const int jB1 = colv[min(pB + SLOTS, lastB)];
        const int jB2 = colv[min(pB + 2 * SLOTS, lastB)];
        const uint4 gA0 = *(const uint4*)(h16 + (size_t)jA0 * IN_W + fqo);
        const uint4 gA1 = *(const uint4*)(h16 + (size_t)jA1 * IN_W + fqo);
        const uint4 gA2 = *(const uint4*)(h16 + (size_t)jA2 * IN_W + fqo);
        const uint4 gB0 = *(const uint4*)(h16 + (size_t)jB0 * IN_W + fqo);
        const uint4 gB1 = *(const uint4*)(h16 + (size_t)jB1 * IN_W + fqo);
        const uint4 gB2 = *(const uint4*)(h16 + (size_t)jB2 * IN_W + fqo);

        __half2 aA[4] = {ZERO2, ZERO2, ZERO2, ZERO2};
        __half2 aB[4] = {ZERO2, ZERO2, ZERO2, ZERO2};
        {
            H2x4 hh;
            const __half2 mA0 = (pA < eA) ? ONE2 : ZERO2;
            const __half2 mA1 = (pA + SLOTS < eA) ? ONE2 : ZERO2;
            const __half2 mA2 = (pA + 2 * SLOTS < eA) ? ONE2 : ZERO2;
            const __half2 mB0 = (pB < eB) ? ONE2 : ZERO2;
            const __half2 mB1 = (pB + SLOTS < eB) ? ONE2 : ZERO2;
            const __half2 mB2 = (pB + 2 * SLOTS < eB) ? ONE2 : ZERO2;
            hh.u = gA0;
#pragma unroll
            for (int t = 0; t < 4; ++t) aA[t] = __hfma2(hh.h[t], mA0, aA[t]);
            hh.u = gA1;
#pragma unroll
            for (int t = 0; t < 4; ++t) aA[t] = __hfma2(hh.h[t], mA1, aA[t]);
            hh.u = gA2;
#pragma unroll
            for (int t = 0; t < 4; ++t) aA[t] = __hfma2(hh.h[t], mA2, aA[t]);
            hh.u = gB0;
#pragma unroll
            for (int t = 0; t < 4; ++t) aB[t] = __hfma2(hh.h[t], mB0, aB[t]);
            hh.u = gB1;
#pragma unroll
            for (int t = 0; t < 4; ++t) aB[t] = __hfma2(hh.h[t], mB1, aB[t]);
            hh.u = gB2;
#pragma unroll
            for (int t = 0; t < 4; ++t) aB[t] = __hfma2(hh.h[t], mB2, aB[t]);
        }
        // rare tails (deg > 3*SLOTS, ~3%): wave-uniform branches
        if (eA - sA > 3 * SLOTS) {
            H2x4 hh;
            for (int p = pA + 3 * SLOTS; p < eA; p += SLOTS) {
                hh.u = *(const uint4*)(h16 + (size_t)colv[p] * IN_W + fqo);
#pragma unroll
                for (int t = 0; t < 4; ++t) aA[t] = __hadd2(aA[t], hh.h[t]);
            }
        }
        if (eB - sB > 3 * SLOTS) {
            H2x4 hh;
            for (int p = pB + 3 * SLOTS; p < eB; p += SLOTS) {
                hh.u = *(const uint4*)(h16 + (size_t)colv[p] * IN_W + fqo);
#pragma unroll
                for (int t = 0; t < 4; ++t) aB[t] = __hadd2(aB[t], hh.h[t]);
            }
        }
        // all-fp16 tree reduce across slots
#pragma unroll
        for (int m = QUADS; m < 64; m <<= 1) {
#pragma unroll
            for (int t = 0; t < 4; ++t) {
                int vA = __shfl_xor(*reinterpret_cast<const int*>(&aA[t]), m, 64);
                int vB = __shfl_xor(*reinterpret_cast<const int*>(&aB[t]), m, 64);
                aA[t] = __hadd2(aA[t], *reinterpret_cast<const __half2*>(&vA));
                aB[t] = __hadd2(aB[t], *reinterpret_cast<const __half2*>(&vB));
            }
        }
        if (slot == 0) {
            const float dA = rdis[rA], dB = rdis[rB];
            H2x4 pA4, pB4;
#pragma unroll
            for (int t = 0; t < 4; ++t) {
                const float2 qA = __half22float2(aA[t]);
                const float2 qB = __half22float2(aB[t]);
                pA4.h[t] = __float22half2_rn(make_float2(qA.x * dA, qA.y * dA));
                pB4.h[t] = __float22half2_rn(make_float2(qB.x * dB, qB.y * dB));
            }
            *(uint4*)&aggT16[rA][fq << 3] = pA4.u;
            *(uint4*)&aggT16[rB][fq << 3] = pB4.u;
        }
    }
    __syncthreads();

    // phase 2: MFMA. Wave w: rows [16w, 16w+16), all 64 cols.
    {
        const int m16 = lane & 15;
        const int quad = lane >> 4;
        const int row0 = wave << 4;
        const half8 a0 = *(const half8*)&aggT16[row0 + m16][quad * 8];
        const half8 a1 = *(const half8*)&aggT16[row0 + m16][32 + quad * 8];
#pragma unroll
        for (int nt = 0; nt < 4; ++nt) {
            const half8 b0 = *(const half8*)&Wt16[nt * 16 + m16][quad * 8];
            const half8 b1 = *(const half8*)&Wt16[nt * 16 + m16][32 + quad * 8];
            f32x4 acc = {0.f, 0.f, 0.f, 0.f};
            acc = __builtin_amdgcn_mfma_f32_16x16x32_f16(a0, b0, acc, 0, 0, 0);
            acc = __builtin_amdgcn_mfma_f32_16x16x32_f16(a1, b1, acc, 0, 0, 0);
            const int col = nt * 16 + m16;
            const float bcol = HAS_BIAS ? bias[col] : 0.f;
#pragma unroll
            for (int t = 0; t < 4; ++t) {
                const int r = row0 + quad * 4 + t;
                const int i = tile0 + r;
                if (i < NN) {
                    float o = acc[t] + bcol;
                    if constexpr (HAS_ADD) o += __half2float(addsrc[(size_t)i * 64 + col]);
                    if constexpr (RELU) o = fmaxf(o, 0.f);
                    if constexpr (WRAW) outraw[(size_t)i * 64 + col] = __float2half(o);
                    if constexpr (W16) out16[(size_t)i * 64 + col] = __float2half(o * rdis[r]);
                }
            }
        }
    }
}

// ---------------- driver ----------------

extern "C" void kernel_launch(void* const* d_in, const int* in_sizes, int n_in,
                              void* d_out, int out_size, void* d_ws, size_t ws_size,
                              hipStream_t stream) {
    const float* x   = (const float*)d_in[0];
    const float* Wp  = (const float*)d_in[1];
    const float* bp  = (const float*)d_in[2];
    const float* Wr  = (const float*)d_in[3];
    const float* br  = (const float*)d_in[4];
    const float* W11 = (const float*)d_in[5];
    const float* b11 = (const float*)d_in[6];
    const float* W12 = (const float*)d_in[7];
    const float* b12 = (const float*)d_in[8];
    const float* W21 = (const float*)d_in[9];
    const float* b21 = (const float*)d_in[10];
    const float* W22 = (const float*)d_in[11];
    const float* b22 = (const float*)d_in[12];
    const float* Wh1 = (const float*)d_in[13];
    const float* bh1 = (const float*)d_in[14];
    const float* Wh2 = (const float*)d_in[15];
    const float* bh2 = (const float*)d_in[16];
    const float* Wh3 = (const float*)d_in[17];
    const float* bh3 = (const float*)d_in[18];
    const int* edge  = (const int*)d_in[19];
    const int* srcA = edge;
    const int* dstA = edge + NE;
    float* outp = (float*)d_out;

    char* p = (char*)d_ws;
    auto carve = [&](size_t bytes) {
        char* r = p;
        p += (bytes + 255) & ~(size_t)255;
        return r;
    };
    int*      cnt   = (int*)carve(NN * 4);
    int*      rptr  = (int*)carve((NN + 1) * 4);
    float*    dis   = (float*)carve(NN * 4);
    int*      sums  = (int*)carve(128 * 4);
    int*      gcnt  = (int*)carve(256 * 4);
    unsigned* bins  = (unsigned*)carve((size_t)NBUCK * BCAP * 4);
    int*      colv  = (int*)carve((size_t)(NE + NN + 256) * 4);
    float4*   xs4   = (float4*)carve((size_t)NN * 16);
    float*    ax    = (float*)carve((size_t)NN * 3 * 4);
    __half*   xr16  = (__half*)carve((size_t)NN * 64 * 2);
    __half*   bu16b = (__half*)carve((size_t)NN * 64 * 2);
    __half*   bw16b = (__half*)carve((size_t)NN * 64 * 2);
    __half*   bt16  = (__half*)carve((size_t)NN * 64 * 2);
    __half*   bu16  = (__half*)carve((size_t)NN * 64 * 2);
    __half*   bv16  = (__half*)carve((size_t)NN * 64 * 2);
    __half*   bw16  = (__half*)carve((size_t)NN * 64 * 2);
    // head reuse (dead after main loop)
    __half*   z1    = bv16;   // NN x 32
    __half*   z2    = bw16;   // NN x 8
    __half*   z3    = bu16;   // NN x 2

    hipMemsetAsync(gcnt, 0, 256 * 4, stream);
    const int GA = (NE + PA_EDGES - 1) / PA_EDGES;
    binA_kernel<<<GA, 256, 0, stream>>>(srcA, dstA, gcnt, bins);
    binB1_kernel<<<NBUCK, 256, 0, stream>>>(bins, gcnt, cnt);
    dis_xs_kernel<<<(NN + 255) / 256, 256, 0, stream>>>(cnt, x, dis, xs4);
    scan1_kernel<<<NCHUNK, 256, 0, stream>>>(cnt, rptr, sums);
    scan2_kernel<<<1, 128, 0, stream>>>(sums, rptr);
    scan3_kernel<<<(NN + 255) / 256, 256, 0, stream>>>(rptr, sums);
    binB2_kernel<<<NBUCK, 256, 0, stream>>>(bins, gcnt, rptr, colv);
    selffill_kernel<<<(NN + 255) / 256, 256, 0, stream>>>(rptr, cnt, colv);
    aggx_kernel<<<(NN + 255) / 256, 256, 0, stream>>>(xs4, rptr, colv, dis, ax);
    proj_kernel<<<(NN * 64 + 255) / 256, 256, 0, stream>>>(ax, Wp, bp, Wr, br, dis, bt16, xr16);

    const int GB = (NN + 63) / 64;
    for (int it = 0; it < 5; ++it) {
        gcn_kernel<false, true, false, true, true><<<GB, 256, 0, stream>>>(
            bt16, Wr, nullptr, xr16, rptr, colv, dis, bu16b, bu16);
        gcn_kernel<true, false, true, false, true><<<GB, 256, 0, stream>>>(
            bu16, W11, b11, nullptr, rptr, colv, dis, nullptr, bv16);
        gcn_kernel<true, true, true, true, true><<<GB, 256, 0, stream>>>(
            bv16, W12, b12, bu16b, rptr, colv, dis, bw16b, bw16);
        gcn_kernel<true, false, true, false, true><<<GB, 256, 0, stream>>>(
            bw16, W21, b21, nullptr, rptr, colv, dis, nullptr, bv16);
        gcn_kernel<true, true, true, false, true><<<GB, 256, 0, stream>>>(
            bv16, W22, b22, bw16b, rptr, colv, dis, nullptr, bt16);
    }
    // head, multiply-first, per-node narrow kernels
    mmh1_kernel<<<(NN * 32 + 255) / 256, 256, 0, stream>>>(bt16, Wh1, z1);
    h32to8_kernel<<<(NN + 255) / 256, 256, 0, stream>>>(z1, rptr, colv, dis, bh1, Wh2, z2);
    h8to2_kernel<<<(NN + 255) / 256, 256, 0, stream>>>(z2, rptr, colv, dis, bh2, Wh3, z3);
    final2_kernel<<<(NN + 255) / 256, 256, 0, stream>>>(z3, rptr, colv, dis, bh3, outp);
}